// Round 19
// baseline (729.089 us; speedup 1.0000x reference)
//
#include <hip/hip_runtime.h>
#include <math.h>

#define NL 10
#define BSZ 2
#define TSEQ 2040
#define TPAD 2048
#define DMOD 256
#define NH 4
#define HDIM 64
#define DFF 1024
#define MPAD (BSZ*TPAD)   // 4096
#define CKV 512           // KV chunk per attention block

typedef __attribute__((ext_vector_type(8))) short bf16x8;
typedef __attribute__((ext_vector_type(4))) short bf16x4;
typedef __attribute__((ext_vector_type(4))) float f32x4;

__device__ __forceinline__ ushort f2b(float f){
  union { float f; unsigned u; } v; v.f = f;
  unsigned u = v.u;
  return (ushort)((u + 0x7FFFu + ((u >> 16) & 1u)) >> 16);
}
__device__ __forceinline__ float b2f(ushort h){
  union { unsigned u; float f; } v; v.u = ((unsigned)h) << 16; return v.f;
}

// ---- copy sequences -> padded x [B][2048][256] f32 (zero pad rows) + row stats ----
__global__ __launch_bounds__(256) void copy_in_k(const float* __restrict__ seq, float* __restrict__ x,
                                                 float* __restrict__ pstat){
  int idx = blockIdx.x * 256 + threadIdx.x;
  int row = idx >> 6, c = idx & 63;
  int b = row >> 11, t = row & 2047;
  float4 v = {0.f, 0.f, 0.f, 0.f};
  if (t < TSEQ) v = ((const float4*)(seq + ((size_t)(b * TSEQ + t)) * DMOD))[c];
  ((float4*)(x + (size_t)row * DMOD))[c] = v;
  float s  = v.x + v.y + v.z + v.w;
  float s2 = v.x*v.x + v.y*v.y + v.z*v.z + v.w*v.w;
  #pragma unroll
  for (int off = 1; off < 16; off <<= 1){ s += __shfl_xor(s, off); s2 += __shfl_xor(s2, off); }
  if ((c & 15) == 0){
    float2 pr; pr.x = s; pr.y = s2;
    ((float2*)pstat)[(size_t)row * 4 + (c >> 4)] = pr;
  }
}

// ---- LDS-tiled transpose+cast: src (L,K,N) f32 -> dst [l][row0+n][k] bf16 ----
__global__ __launch_bounds__(256) void wtrans_k(const float* __restrict__ src, ushort* __restrict__ dst,
                                                int N, int K, int NTOT, int row0){
  __shared__ ushort tile[64][72];
  int tid = threadIdx.x;
  int kk0 = blockIdx.x * 64, n0 = blockIdx.y * 64, l = blockIdx.z;
  int kl = tid >> 2, nq = tid & 3;
  const float* sp = src + ((size_t)(l * K + kk0 + kl)) * N + n0 + nq * 16;
  #pragma unroll
  for (int i = 0; i < 4; ++i){
    float4 v = ((const float4*)sp)[i];
    int nb = nq * 16 + i * 4;
    tile[nb + 0][kl] = f2b(v.x);
    tile[nb + 1][kl] = f2b(v.y);
    tile[nb + 2][kl] = f2b(v.z);
    tile[nb + 3][kl] = f2b(v.w);
  }
  __syncthreads();
  int r = tid >> 2, cq = (tid & 3) * 16;
  ushort* dp = dst + ((size_t)(l * NTOT + row0 + n0 + r)) * K + kk0 + cq;
  *(bf16x8*)dp       = *(const bf16x8*)&tile[r][cq];
  *(bf16x8*)(dp + 8) = *(const bf16x8*)&tile[r][cq + 8];
}

// ---- concat qkv biases ----
__global__ __launch_bounds__(256) void bqkv_k(const float* __restrict__ bq, const float* __restrict__ bk,
                                              const float* __restrict__ bv, float* __restrict__ bqkv){
  int idx = blockIdx.x * 256 + threadIdx.x;
  if (idx >= NL * 768) return;
  int l = idx / 768, n = idx % 768;
  float v = (n < 256) ? bq[l * 256 + n] : ((n < 512) ? bk[l * 256 + n - 256] : bv[l * 256 + n - 512]);
  bqkv[idx] = v;
}

// ---- final layernorm -> f32 d_out (compact rows); 4 rows per block ----
__global__ __launch_bounds__(256) void lnf_k(const float* __restrict__ x, const float* __restrict__ g,
                                             const float* __restrict__ be, float* __restrict__ outf){
  int tid = threadIdx.x;
  int row = blockIdx.x * 4 + (tid >> 6), lane = tid & 63;
  int b = row / TSEQ, t = row % TSEQ;
  int irow = b * TPAD + t;
  float4 xv = ((const float4*)(x + (size_t)irow * DMOD))[lane];
  float s  = xv.x + xv.y + xv.z + xv.w;
  float s2 = xv.x*xv.x + xv.y*xv.y + xv.z*xv.z + xv.w*xv.w;
  #pragma unroll
  for (int off = 1; off < 64; off <<= 1){ s += __shfl_xor(s, off); s2 += __shfl_xor(s2, off); }
  float mu = s * (1.f/256.f);
  float var = s2 * (1.f/256.f) - mu * mu;
  float rs = rsqrtf(var + 1e-5f);
  float4 gv = ((const float4*)g)[lane];
  float4 bv = ((const float4*)be)[lane];
  float4 ov;
  ov.x = (xv.x - mu) * rs * gv.x + bv.x;
  ov.y = (xv.y - mu) * rs * gv.y + bv.y;
  ov.z = (xv.z - mu) * rs * gv.z + bv.z;
  ov.w = (xv.w - mu) * rs * gv.w + bv.w;
  ((float4*)(outf + (size_t)row * DMOD))[lane] = ov;
}

// ---- BMx64-tile GEMM, BK=128 ----
// BM=64: 4 waves as 2x2 (32x32 each). BM=32: 4 waves as 1x4 (32x16 each).
// AMODE 0: A = Ab; AMODE 1: A = LN(Af) via pstat_in; AMODE 2: A = merged attn
// EPI 0: QKV scatter (q pre-scaled; v [b,h,hd,t]); EPI 1: xres += v; EPI 2: GELU -> o0
// STATS 1: per-(row, colblock64) partial {sum,sumsq} of x_new -> pstat_out
template<int N, int K, int AMODE, int EPI, int STATS, int BM>
__global__ __launch_bounds__(256) void gemm_k(
    const ushort* __restrict__ Ab, const float* __restrict__ Af,
    const float* __restrict__ pstat_in, const float* __restrict__ lng, const float* __restrict__ lnb,
    const ushort* __restrict__ po, const float* __restrict__ pml,
    const ushort* __restrict__ Bt, const float* __restrict__ bias,
    float* __restrict__ xres, float* __restrict__ pstat_out,
    ushort* __restrict__ o0, ushort* __restrict__ o1, ushort* __restrict__ o2){
  constexpr int NC = (BM == 64) ? 2 : 1;      // col fragments per wave
  constexpr int NW = (BM == 64) ? 2 : 4;      // col groups (waves in col dim)
  __shared__ ushort Alds[2][BM][72];
  __shared__ ushort Blds[2][64][72];
  __shared__ float statLds[STATS ? BM : 1][NW][2];
  int tid = threadIdx.x;
  int w = tid >> 6, lane = tid & 63;
  int wr = (BM == 64) ? (w >> 1) : 0;
  int wc = (BM == 64) ? (w & 1) : w;
  int l15 = lane & 15, l4 = lane >> 4;
  int row0 = blockIdx.x * BM, col0 = blockIdx.y * 64;
  int r = tid >> 3, c8 = (tid & 7) * 8;       // r in [0,32)

  float muA = 0.f, rsA = 0.f, muB = 0.f, rsB = 0.f;
  if (AMODE == 1){
    const float4* pa = (const float4*)(pstat_in + (size_t)(row0 + r) * 8);
    float4 a0 = pa[0], a1 = pa[1];
    float s = a0.x + a0.z + a1.x + a1.z, q = a0.y + a0.w + a1.y + a1.w;
    muA = s * (1.f/256.f);
    rsA = rsqrtf(q * (1.f/256.f) - muA * muA + 1e-5f);
    if (BM == 64){
      const float4* pb = (const float4*)(pstat_in + (size_t)(row0 + r + 32) * 8);
      float4 b0 = pb[0], b1 = pb[1];
      s = b0.x + b0.z + b1.x + b1.z; q = b0.y + b0.w + b1.y + b1.w;
      muB = s * (1.f/256.f);
      rsB = rsqrtf(q * (1.f/256.f) - muB * muB + 1e-5f);
    }
  }

  f32x4 zero = {0.f, 0.f, 0.f, 0.f};
  f32x4 acc[2][NC];
  #pragma unroll
  for (int mr = 0; mr < 2; ++mr)
    #pragma unroll
    for (int nc = 0; nc < NC; ++nc) acc[mr][nc] = zero;

  for (int k0 = 0; k0 < K; k0 += 128){
    #pragma unroll
    for (int ck = 0; ck < 2; ++ck){
      int kk = k0 + ck * 64;
      // ---- stage A (BM rows) ----
      #pragma unroll
      for (int it = 0; it < BM / 32; ++it){
        int rr = r + it * 32;
        if (AMODE == 0){
          *(bf16x8*)&Alds[ck][rr][c8] = *(const bf16x8*)(Ab + (size_t)(row0 + rr) * K + kk + c8);
        } else if (AMODE == 1){
          float mu = it ? muB : muA, rs = it ? rsB : rsA;
          const float4* xp = (const float4*)(Af + (size_t)(row0 + rr) * 256 + kk + c8);
          float4 xa = xp[0], xb = xp[1];
          const float4* gp = (const float4*)(lng + kk + c8);
          const float4* bp = (const float4*)(lnb + kk + c8);
          float4 ga = gp[0], gb = gp[1], ba = bp[0], bb = bp[1];
          bf16x8 pk;
          pk[0] = (short)f2b((xa.x - mu) * rs * ga.x + ba.x);
          pk[1] = (short)f2b((xa.y - mu) * rs * ga.y + ba.y);
          pk[2] = (short)f2b((xa.z - mu) * rs * ga.z + ba.z);
          pk[3] = (short)f2b((xa.w - mu) * rs * ga.w + ba.w);
          pk[4] = (short)f2b((xb.x - mu) * rs * gb.x + bb.x);
          pk[5] = (short)f2b((xb.y - mu) * rs * gb.y + bb.y);
          pk[6] = (short)f2b((xb.z - mu) * rs * gb.z + bb.z);
          pk[7] = (short)f2b((xb.w - mu) * rs * gb.w + bb.w);
          *(bf16x8*)&Alds[ck][rr][c8] = pk;
        } else {
          int m = row0 + rr;
          int t = m & 2047, b_ = m >> 11;
          int qt = t >> 4, r16 = t & 15;
          int hh = kk >> 6;
          int u0 = (((b_ * NH + hh) << 7) + qt) << 2;
          int je = ((qt * 16 + 15) / 17) * 17 + 17; je = je < TSEQ ? je : TSEQ;
          int nch = (je + CKV - 1) >> 9;
          float mm[4]; float mg = -1e30f;
          #pragma unroll
          for (int ch = 0; ch < 4; ++ch){
            mm[ch] = (ch < nch) ? pml[(size_t)(u0 + ch) * 32 + r16 * 2] : -1e30f;
            mg = fmaxf(mg, mm[ch]);
          }
          float aw[4]; float lg = 0.f;
          #pragma unroll
          for (int ch = 0; ch < 4; ++ch){
            float ll = (ch < nch) ? pml[(size_t)(u0 + ch) * 32 + r16 * 2 + 1] : 0.f;
            aw[ch] = (ch < nch) ? __expf(mm[ch] - mg) : 0.f;
            lg += aw[ch] * ll;
          }
          float inv = 1.f / lg;
          float av[8] = {0.f,0.f,0.f,0.f,0.f,0.f,0.f,0.f};
          #pragma unroll
          for (int ch = 0; ch < 4; ++ch){
            bf16x8 pv = *(const bf16x8*)(po + (size_t)(u0 + ch) * 1024 + r16 * 64 + c8);
            #pragma unroll
            for (int j = 0; j < 8; ++j) av[j] += aw[ch] * b2f((ushort)pv[j]);
          }
          bf16x8 pk;
          #pragma unroll
          for (int j = 0; j < 8; ++j) pk[j] = (short)f2b(av[j] * inv);
          *(bf16x8*)&Alds[ck][rr][c8] = pk;
        }
      }
      // ---- stage B (64 rows) ----
      #pragma unroll
      for (int it = 0; it < 2; ++it){
        int rr = r + it * 32;
        *(bf16x8*)&Blds[ck][rr][c8] = *(const bf16x8*)(Bt + (size_t)(col0 + rr) * K + kk + c8);
      }
    }
    __syncthreads();
    #pragma unroll
    for (int ck = 0; ck < 2; ++ck){
      #pragma unroll
      for (int ks = 0; ks < 2; ++ks){
        bf16x8 af[2], bfr[NC];
        #pragma unroll
        for (int i = 0; i < 2; ++i)
          af[i] = *(const bf16x8*)&Alds[ck][wr * 32 + i * 16 + l15][ks * 32 + l4 * 8];
        #pragma unroll
        for (int i = 0; i < NC; ++i)
          bfr[i] = *(const bf16x8*)&Blds[ck][wc * (16 * NC) + i * 16 + l15][ks * 32 + l4 * 8];
        #pragma unroll
        for (int mr = 0; mr < 2; ++mr)
          #pragma unroll
          for (int nc = 0; nc < NC; ++nc)
            acc[mr][nc] = __builtin_amdgcn_mfma_f32_16x16x32_bf16(af[mr], bfr[nc], acc[mr][nc], 0, 0, 0);
      }
    }
    __syncthreads();
  }

  float sr_[2][4], q2_[2][4];
  if (STATS){
    #pragma unroll
    for (int mr = 0; mr < 2; ++mr)
      #pragma unroll
      for (int rr = 0; rr < 4; ++rr){ sr_[mr][rr] = 0.f; q2_[mr][rr] = 0.f; }
  }
  #pragma unroll
  for (int mr = 0; mr < 2; ++mr){
    #pragma unroll
    for (int nc = 0; nc < NC; ++nc){
      #pragma unroll
      for (int rr = 0; rr < 4; ++rr){
        int m = row0 + wr * 32 + mr * 16 + l4 * 4 + rr;
        int n = col0 + wc * (16 * NC) + nc * 16 + l15;
        float v = acc[mr][nc][rr] + bias[n];
        if (EPI == 0){
          int b = m >> 11, t = m & 2047;
          int which = n >> 8, hn = n & 255, hh = hn >> 6, hd = hn & 63;
          if (which == 0)      o0[(((size_t)(b * NH + hh)) * TPAD + t) * HDIM + hd] = f2b(v * 0.125f);
          else if (which == 1) o1[(((size_t)(b * NH + hh)) * TPAD + t) * HDIM + hd] = f2b(v);
          else                 o2[(((size_t)(b * NH + hh)) * HDIM + hd) * TPAD + t] = f2b(v);
        } else if (EPI == 1){
          float xn = xres[(size_t)m * 256 + n] + v;
          xres[(size_t)m * 256 + n] = xn;
          if (STATS){ sr_[mr][rr] += xn; q2_[mr][rr] += xn * xn; }
        } else {
          float uu = 0.7978845608028654f * (v + 0.044715f * v * v * v);
          float e = __expf(2.f * uu);
          float th = 1.f - 2.f / (e + 1.f);
          o0[(size_t)m * N + n] = f2b(0.5f * v * (1.f + th));
        }
      }
    }
  }
  if (STATS){
    #pragma unroll
    for (int mr = 0; mr < 2; ++mr){
      #pragma unroll
      for (int rr = 0; rr < 4; ++rr){
        float s = sr_[mr][rr], q = q2_[mr][rr];
        #pragma unroll
        for (int off = 1; off < 16; off <<= 1){ s += __shfl_xor(s, off); q += __shfl_xor(q, off); }
        if (l15 == 0){
          int rl = wr * 32 + mr * 16 + l4 * 4 + rr;
          statLds[rl][wc][0] = s;
          statLds[rl][wc][1] = q;
        }
      }
    }
    __syncthreads();
    if (tid < BM){
      float ssum = 0.f, qsum = 0.f;
      #pragma unroll
      for (int g = 0; g < NW; ++g){ ssum += statLds[tid][g][0]; qsum += statLds[tid][g][1]; }
      float2 pr; pr.x = ssum; pr.y = qsum;
      ((float2*)pstat_out)[(size_t)(row0 + tid) * 4 + blockIdx.y] = pr;
    }
  }
}

// ---- split-KV flash attention: swapped-operand QK^T, per-lane softmax,
//      defer-max rescale (T13) + setprio around MFMA clusters (T5) ----
// block = (qg 64 q-rows, ch 512-KV chunk, bh); grid (32,4,8); 4 waves x 16 q each.
__global__ __launch_bounds__(256) void attn_tile_k(const ushort* __restrict__ qq, const ushort* __restrict__ kkk,
                                                   const ushort* __restrict__ vt,
                                                   ushort* __restrict__ po, float* __restrict__ pml){
  __shared__ ushort Klds[64][72];
  __shared__ ushort Vlds[64][72];
  __shared__ ushort Plds[4][16][72];
  int tid = threadIdx.x, w = tid >> 6, lane = tid & 63;
  int l15 = lane & 15, l4 = lane >> 4;
  int qg = blockIdx.x, ch = blockIdx.y, bh = blockIdx.z;
  int r0 = qg * 64;
  int je_blk = ((r0 + 63) / 17 + 1) * 17; je_blk = je_blk < TSEQ ? je_blk : TSEQ;
  int jstart = ch * CKV;
  if (jstart >= je_blk) return;                       // idle block (uniform)
  int jend = (jstart + CKV) < je_blk ? (jstart + CKV) : je_blk;

  int i0 = r0 + w * 16;
  int je_w = ((i0 + 15) / 17 + 1) * 17; je_w = je_w < TSEQ ? je_w : TSEQ;

  const ushort* qb = qq  + (size_t)bh * TPAD * HDIM;
  const ushort* kb = kkk + (size_t)bh * TPAD * HDIM;
  const ushort* vb = vt  + (size_t)bh * HDIM * TPAD;

  int ig = i0 + l15;                                  // this lane's query row
  int ibase = (int)((unsigned)ig / 17u) * 17;         // its block start
  bf16x8 aq0 = *(const bf16x8*)(qb + (size_t)ig * HDIM + l4 * 8);
  bf16x8 aq1 = *(const bf16x8*)(qb + (size_t)ig * HDIM + 32 + l4 * 8);

  f32x4 zero = {0.f, 0.f, 0.f, 0.f};
  float m_ = -1e30f, l_ = 0.f;
  f32x4 o_[4];
  o_[0] = zero; o_[1] = zero; o_[2] = zero; o_[3] = zero;

  int sr = tid >> 2, sc = (tid & 3) * 16;             // staging: 4 threads/row, 32B each
  for (int j0 = jstart; j0 < jend; j0 += 64){
    __syncthreads();
    *(bf16x8*)&Klds[sr][sc]     = *(const bf16x8*)(kb + (size_t)(j0 + sr) * HDIM + sc);
    *(bf16x8*)&Klds[sr][sc + 8] = *(const bf16x8*)(kb + (size_t)(j0 + sr) * HDIM + sc + 8);
    *(bf16x8*)&Vlds[sr][sc]     = *(const bf16x8*)(vb + (size_t)sr * TPAD + j0 + sc);
    *(bf16x8*)&Vlds[sr][sc + 8] = *(const bf16x8*)(vb + (size_t)sr * TPAD + j0 + sc + 8);
    __syncthreads();
    if (j0 >= je_w) continue;
    f32x4 s[4];
    __builtin_amdgcn_s_setprio(1);
    #pragma unroll
    for (int f = 0; f < 4; ++f){
      bf16x8 kf = *(const bf16x8*)&Klds[f * 16 + l15][l4 * 8];
      s[f] = __builtin_amdgcn_mfma_f32_16x16x32_bf16(kf, aq0, zero, 0, 0, 0);
    }
    #pragma unroll
    for (int f = 0; f < 4; ++f){
      bf16x8 kf = *(const bf16x8*)&Klds[f * 16 + l15][32 + l4 * 8];
      s[f] = __builtin_amdgcn_mfma_f32_16x16x32_bf16(kf, aq1, s[f], 0, 0, 0);
    }
    __builtin_amdgcn_s_setprio(0);
    if (j0 + 63 > i0){
      #pragma unroll
      for (int f = 0; f < 4; ++f){
        #pragma unroll
        for (int rr = 0; rr < 4; ++rr){
          int jg = j0 + f * 16 + l4 * 4 + rr;
          bool ok = (jg <= ig) || ((unsigned)(jg - ibase) < 17u);
          s[f][rr] = ok ? s[f][rr] : -1e30f;
        }
      }
    }
    float mf0 = fmaxf(fmaxf(s[0][0], s[0][1]), fmaxf(s[0][2], s[0][3]));
    float mf1 = fmaxf(fmaxf(s[1][0], s[1][1]), fmaxf(s[1][2], s[1][3]));
    float mf2 = fmaxf(fmaxf(s[2][0], s[2][1]), fmaxf(s[2][2], s[2][3]));
    float mf3 = fmaxf(fmaxf(s[3][0], s[3][1]), fmaxf(s[3][2], s[3][3]));
    float mx = fmaxf(fmaxf(mf0, mf1), fmaxf(mf2, mf3));
    mx = fmaxf(mx, __shfl_xor(mx, 16));
    mx = fmaxf(mx, __shfl_xor(mx, 32));
    // defer-max: skip O/l rescale when max growth is bounded (P <= e^8, bf16-safe)
    float mn = m_;
    if (!__all(mx - m_ <= 8.f)){
      mn = fmaxf(m_, mx);
      float alpha = __expf(m_ - mn);
      l_ *= alpha;
      #pragma unroll
      for (int f = 0; f < 4; ++f) o_[f] *= alpha;
      m_ = mn;
    }
    float ps = 0.f;
    #pragma unroll
    for (int f = 0; f < 4; ++f){
      bf16x4 pk;
      #pragma unroll
      for (int rr = 0; rr < 4; ++rr){
        float p = __expf(s[f][rr] - mn);
        ps += p;
        pk[rr] = (short)f2b(p);
      }
      *(bf16x4*)&Plds[w][l15][f * 16 + l4 * 4] = pk;
    }
    ps += __shfl_xor(ps, 16);
    ps += __shfl_xor(ps, 32);
    l_ += ps;
    __builtin_amdgcn_s_setprio(1);
    #pragma unroll
    for (int ks = 0; ks < 2; ++ks){
      bf16x8 pf = *(const bf16x8*)&Plds[w][l15][ks * 32 + l4 * 8];
      #pragma unroll
      for (int f = 0; f < 4; ++f){
        bf16x8 vf = *(const bf16x8*)&Vlds[f * 16 + l15][ks * 32 + l4 * 8];
        o_[f] = __builtin_amdgcn_mfma_f32_16x16x32_bf16(vf, pf, o_[f], 0, 0, 0);
      }
    }
    __builtin_amdgcn_s_setprio(0);
  }
  int qt = qg * 4 + w;
  int u = ((bh << 7) + qt) * 4 + ch;
  size_t ob = (size_t)u * 1024;
  #pragma unroll
  for (int f = 0; f < 4; ++f){
    bf16x4 pk;
    #pragma unroll
    for (int rr = 0; rr < 4; ++rr) pk[rr] = (short)f2b(o_[f][rr]);
    *(bf16x4*)&po[ob + (size_t)l15 * 64 + f * 16 + l4 * 4] = pk;
  }
  if (l4 == 0){
    pml[(size_t)u * 32 + l15 * 2 + 0] = m_;
    pml[(size_t)u * 32 + l15 * 2 + 1] = l_;
  }
}

extern "C" void kernel_launch(void* const* d_in, const int* in_sizes, int n_in,
                              void* d_out, int out_size, void* d_ws, size_t ws_size,
                              hipStream_t stream){
  const float* seq    = (const float*)d_in[0];
  const float* ln1_g  = (const float*)d_in[1];
  const float* ln1_b  = (const float*)d_in[2];
  const float* wq     = (const float*)d_in[3];
  const float* bq     = (const float*)d_in[4];
  const float* wk     = (const float*)d_in[5];
  const float* bk     = (const float*)d_in[6];
  const float* wv     = (const float*)d_in[7];
  const float* bv     = (const float*)d_in[8];
  const float* wproj  = (const float*)d_in[9];
  const float* bproj  = (const float*)d_in[10];
  const float* ln2_g  = (const float*)d_in[11];
  const float* ln2_b  = (const float*)d_in[12];
  const float* w1     = (const float*)d_in[13];
  const float* b1     = (const float*)d_in[14];
  const float* w2     = (const float*)d_in[15];
  const float* b2     = (const float*)d_in[16];
  const float* lnf_g  = (const float*)d_in[17];
  const float* lnf_b  = (const float*)d_in[18];

  size_t off = 0;
  char* base = (char*)d_ws;
  auto carve = [&](size_t bytes) -> void* {
    void* p = base + off;
    off += (bytes + 255) & ~(size_t)255;
    return p;
  };
  float*  x      = (float*) carve((size_t)MPAD * DMOD * 4);
  ushort* qbuf   = (ushort*)carve((size_t)BSZ * NH * TPAD * HDIM * 2);
  ushort* kbuf   = (ushort*)carve((size_t)BSZ * NH * TPAD * HDIM * 2);
  ushort* vtbuf  = (ushort*)carve((size_t)BSZ * NH * TPAD * HDIM * 2);
  ushort* mid    = (ushort*)carve((size_t)MPAD * DFF * 2);
  ushort* wqkvT  = (ushort*)carve((size_t)NL * 768 * 256 * 2);
  ushort* wprojT = (ushort*)carve((size_t)NL * 256 * 256 * 2);
  ushort* w1T    = (ushort*)carve((size_t)NL * 1024 * 256 * 2);
  ushort* w2T    = (ushort*)carve((size_t)NL * 256 * 1024 * 2);
  float*  bqkv   = (float*) carve((size_t)NL * 768 * 4);
  ushort* po     = (ushort*)carve((size_t)4096 * 1024 * 2);
  float*  pml    = (float*) carve((size_t)4096 * 32 * 4);
  float*  pstatA = (float*) carve((size_t)MPAD * 8 * 4);
  float*  pstatB = (float*) carve((size_t)MPAD * 8 * 4);
  if (off > ws_size) return;

  // prep
  copy_in_k<<<dim3(MPAD/4), dim3(256), 0, stream>>>(seq, x, pstatA);
  wtrans_k<<<dim3(4, 4, NL),  dim3(256), 0, stream>>>(wq,    wqkvT,  256, 256,  768, 0);
  wtrans_k<<<dim3(4, 4, NL),  dim3(256), 0, stream>>>(wk,    wqkvT,  256, 256,  768, 256);
  wtrans_k<<<dim3(4, 4, NL),  dim3(256), 0, stream>>>(wv,    wqkvT,  256, 256,  768, 512);
  wtrans_k<<<dim3(4, 4, NL),  dim3(256), 0, stream>>>(wproj, wprojT, 256, 256,  256, 0);
  wtrans_k<<<dim3(4, 16, NL), dim3(256), 0, stream>>>(w1,    w1T,   1024, 256, 1024, 0);
  wtrans_k<<<dim3(16, 4, NL), dim3(256), 0, stream>>>(w2,    w2T,    256,1024,  256, 0);
  bqkv_k<<<dim3((NL*768 + 255)/256), dim3(256), 0, stream>>>(bq, bk, bv, bqkv);

  for (int l = 0; l < NL; ++l){
    gemm_k<768,256,1,0,0,32><<<dim3(128,12), dim3(256), 0, stream>>>(
        nullptr, x, pstatA, ln1_g + l*256, ln1_b + l*256, nullptr, nullptr,
        wqkvT + (size_t)l*768*256, bqkv + l*768, nullptr, nullptr, qbuf, kbuf, vtbuf);
    attn_tile_k<<<dim3(32,4,8), dim3(256), 0, stream>>>(qbuf, kbuf, vtbuf, po, pml);
    gemm_k<256,256,2,1,1,32><<<dim3(128,4), dim3(256), 0, stream>>>(
        nullptr, nullptr, nullptr, nullptr, nullptr, po, pml,
        wprojT + (size_t)l*256*256, bproj + l*256, x, pstatB, nullptr, nullptr, nullptr);
    gemm_k<1024,256,1,2,0,32><<<dim3(128,16), dim3(256), 0, stream>>>(
        nullptr, x, pstatB, ln2_g + l*256, ln2_b + l*256, nullptr, nullptr,
        w1T + (size_t)l*1024*256, b1 + l*1024, nullptr, nullptr, mid, nullptr, nullptr);
    gemm_k<256,1024,0,1,1,32><<<dim3(128,4), dim3(256), 0, stream>>>(
        mid, nullptr, nullptr, nullptr, nullptr, nullptr, nullptr,
        w2T + (size_t)l*256*1024, b2 + l*256, x, pstatA, nullptr, nullptr, nullptr);
  }
  lnf_k<<<dim3(BSZ*TSEQ/4), dim3(256), 0, stream>>>(x, lnf_g, lnf_b, (float*)d_out);
}

// Round 20
// 653.295 us; speedup vs baseline: 1.1160x; 1.1160x over previous
//
#include <hip/hip_runtime.h>
#include <math.h>

#define NL 10
#define BSZ 2
#define TSEQ 2040
#define TPAD 2048
#define DMOD 256
#define NH 4
#define HDIM 64
#define DFF 1024
#define MPAD (BSZ*TPAD)   // 4096
#define CKV 512           // KV chunk per attention block

typedef __attribute__((ext_vector_type(8))) short bf16x8;
typedef __attribute__((ext_vector_type(4))) short bf16x4;
typedef __attribute__((ext_vector_type(4))) float f32x4;

__device__ __forceinline__ ushort f2b(float f){
  union { float f; unsigned u; } v; v.f = f;
  unsigned u = v.u;
  return (ushort)((u + 0x7FFFu + ((u >> 16) & 1u)) >> 16);
}
__device__ __forceinline__ float b2f(ushort h){
  union { unsigned u; float f; } v; v.u = ((unsigned)h) << 16; return v.f;
}

// ---- copy sequences -> padded x [B][2048][256] f32 (zero pad rows) + row stats ----
__global__ __launch_bounds__(256) void copy_in_k(const float* __restrict__ seq, float* __restrict__ x,
                                                 float* __restrict__ pstat){
  int idx = blockIdx.x * 256 + threadIdx.x;
  int row = idx >> 6, c = idx & 63;
  int b = row >> 11, t = row & 2047;
  float4 v = {0.f, 0.f, 0.f, 0.f};
  if (t < TSEQ) v = ((const float4*)(seq + ((size_t)(b * TSEQ + t)) * DMOD))[c];
  ((float4*)(x + (size_t)row * DMOD))[c] = v;
  float s  = v.x + v.y + v.z + v.w;
  float s2 = v.x*v.x + v.y*v.y + v.z*v.z + v.w*v.w;
  #pragma unroll
  for (int off = 1; off < 16; off <<= 1){ s += __shfl_xor(s, off); s2 += __shfl_xor(s2, off); }
  if ((c & 15) == 0){
    float2 pr; pr.x = s; pr.y = s2;
    ((float2*)pstat)[(size_t)row * 4 + (c >> 4)] = pr;
  }
}

// ---- LDS-tiled transpose+cast: src (L,K,N) f32 -> dst [l][row0+n][k] bf16 ----
__global__ __launch_bounds__(256) void wtrans_k(const float* __restrict__ src, ushort* __restrict__ dst,
                                                int N, int K, int NTOT, int row0){
  __shared__ ushort tile[64][72];
  int tid = threadIdx.x;
  int kk0 = blockIdx.x * 64, n0 = blockIdx.y * 64, l = blockIdx.z;
  int kl = tid >> 2, nq = tid & 3;
  const float* sp = src + ((size_t)(l * K + kk0 + kl)) * N + n0 + nq * 16;
  #pragma unroll
  for (int i = 0; i < 4; ++i){
    float4 v = ((const float4*)sp)[i];
    int nb = nq * 16 + i * 4;
    tile[nb + 0][kl] = f2b(v.x);
    tile[nb + 1][kl] = f2b(v.y);
    tile[nb + 2][kl] = f2b(v.z);
    tile[nb + 3][kl] = f2b(v.w);
  }
  __syncthreads();
  int r = tid >> 2, cq = (tid & 3) * 16;
  ushort* dp = dst + ((size_t)(l * NTOT + row0 + n0 + r)) * K + kk0 + cq;
  *(bf16x8*)dp       = *(const bf16x8*)&tile[r][cq];
  *(bf16x8*)(dp + 8) = *(const bf16x8*)&tile[r][cq + 8];
}

// ---- concat qkv biases ----
__global__ __launch_bounds__(256) void bqkv_k(const float* __restrict__ bq, const float* __restrict__ bk,
                                              const float* __restrict__ bv, float* __restrict__ bqkv){
  int idx = blockIdx.x * 256 + threadIdx.x;
  if (idx >= NL * 768) return;
  int l = idx / 768, n = idx % 768;
  float v = (n < 256) ? bq[l * 256 + n] : ((n < 512) ? bk[l * 256 + n - 256] : bv[l * 256 + n - 512]);
  bqkv[idx] = v;
}

// ---- final layernorm -> f32 d_out (compact rows); 4 rows per block ----
__global__ __launch_bounds__(256) void lnf_k(const float* __restrict__ x, const float* __restrict__ g,
                                             const float* __restrict__ be, float* __restrict__ outf){
  int tid = threadIdx.x;
  int row = blockIdx.x * 4 + (tid >> 6), lane = tid & 63;
  int b = row / TSEQ, t = row % TSEQ;
  int irow = b * TPAD + t;
  float4 xv = ((const float4*)(x + (size_t)irow * DMOD))[lane];
  float s  = xv.x + xv.y + xv.z + xv.w;
  float s2 = xv.x*xv.x + xv.y*xv.y + xv.z*xv.z + xv.w*xv.w;
  #pragma unroll
  for (int off = 1; off < 64; off <<= 1){ s += __shfl_xor(s, off); s2 += __shfl_xor(s2, off); }
  float mu = s * (1.f/256.f);
  float var = s2 * (1.f/256.f) - mu * mu;
  float rs = rsqrtf(var + 1e-5f);
  float4 gv = ((const float4*)g)[lane];
  float4 bv = ((const float4*)be)[lane];
  float4 ov;
  ov.x = (xv.x - mu) * rs * gv.x + bv.x;
  ov.y = (xv.y - mu) * rs * gv.y + bv.y;
  ov.z = (xv.z - mu) * rs * gv.z + bv.z;
  ov.w = (xv.w - mu) * rs * gv.w + bv.w;
  ((float4*)(outf + (size_t)row * DMOD))[lane] = ov;
}

// ---- BMx64-tile GEMM, BK=128 ----
// BM=64: 4 waves as 2x2 (32x32 each). BM=32: 4 waves as 1x4 (32x16 each).
// AMODE 0: A = Ab; AMODE 1: A = LN(Af) via pstat_in; AMODE 2: A = merged attn
// EPI 0: QKV scatter (q pre-scaled; v [b,h,hd,t]); EPI 1: xres += v; EPI 2: GELU -> o0
// STATS 1: per-(row, colblock64) partial {sum,sumsq} of x_new -> pstat_out
template<int N, int K, int AMODE, int EPI, int STATS, int BM>
__global__ __launch_bounds__(256) void gemm_k(
    const ushort* __restrict__ Ab, const float* __restrict__ Af,
    const float* __restrict__ pstat_in, const float* __restrict__ lng, const float* __restrict__ lnb,
    const ushort* __restrict__ po, const float* __restrict__ pml,
    const ushort* __restrict__ Bt, const float* __restrict__ bias,
    float* __restrict__ xres, float* __restrict__ pstat_out,
    ushort* __restrict__ o0, ushort* __restrict__ o1, ushort* __restrict__ o2){
  constexpr int NC = (BM == 64) ? 2 : 1;      // col fragments per wave
  constexpr int NW = (BM == 64) ? 2 : 4;      // col groups (waves in col dim)
  __shared__ ushort Alds[2][BM][72];
  __shared__ ushort Blds[2][64][72];
  __shared__ float statLds[STATS ? BM : 1][NW][2];
  int tid = threadIdx.x;
  int w = tid >> 6, lane = tid & 63;
  int wr = (BM == 64) ? (w >> 1) : 0;
  int wc = (BM == 64) ? (w & 1) : w;
  int l15 = lane & 15, l4 = lane >> 4;
  int row0 = blockIdx.x * BM, col0 = blockIdx.y * 64;
  int r = tid >> 3, c8 = (tid & 7) * 8;       // r in [0,32)

  float muA = 0.f, rsA = 0.f, muB = 0.f, rsB = 0.f;
  if (AMODE == 1){
    const float4* pa = (const float4*)(pstat_in + (size_t)(row0 + r) * 8);
    float4 a0 = pa[0], a1 = pa[1];
    float s = a0.x + a0.z + a1.x + a1.z, q = a0.y + a0.w + a1.y + a1.w;
    muA = s * (1.f/256.f);
    rsA = rsqrtf(q * (1.f/256.f) - muA * muA + 1e-5f);
    if (BM == 64){
      const float4* pb = (const float4*)(pstat_in + (size_t)(row0 + r + 32) * 8);
      float4 b0 = pb[0], b1 = pb[1];
      s = b0.x + b0.z + b1.x + b1.z; q = b0.y + b0.w + b1.y + b1.w;
      muB = s * (1.f/256.f);
      rsB = rsqrtf(q * (1.f/256.f) - muB * muB + 1e-5f);
    }
  }

  f32x4 zero = {0.f, 0.f, 0.f, 0.f};
  f32x4 acc[2][NC];
  #pragma unroll
  for (int mr = 0; mr < 2; ++mr)
    #pragma unroll
    for (int nc = 0; nc < NC; ++nc) acc[mr][nc] = zero;

  for (int k0 = 0; k0 < K; k0 += 128){
    #pragma unroll
    for (int ck = 0; ck < 2; ++ck){
      int kk = k0 + ck * 64;
      // ---- stage A (BM rows) ----
      #pragma unroll
      for (int it = 0; it < BM / 32; ++it){
        int rr = r + it * 32;
        if (AMODE == 0){
          *(bf16x8*)&Alds[ck][rr][c8] = *(const bf16x8*)(Ab + (size_t)(row0 + rr) * K + kk + c8);
        } else if (AMODE == 1){
          float mu = it ? muB : muA, rs = it ? rsB : rsA;
          const float4* xp = (const float4*)(Af + (size_t)(row0 + rr) * 256 + kk + c8);
          float4 xa = xp[0], xb = xp[1];
          const float4* gp = (const float4*)(lng + kk + c8);
          const float4* bp = (const float4*)(lnb + kk + c8);
          float4 ga = gp[0], gb = gp[1], ba = bp[0], bb = bp[1];
          bf16x8 pk;
          pk[0] = (short)f2b((xa.x - mu) * rs * ga.x + ba.x);
          pk[1] = (short)f2b((xa.y - mu) * rs * ga.y + ba.y);
          pk[2] = (short)f2b((xa.z - mu) * rs * ga.z + ba.z);
          pk[3] = (short)f2b((xa.w - mu) * rs * ga.w + ba.w);
          pk[4] = (short)f2b((xb.x - mu) * rs * gb.x + bb.x);
          pk[5] = (short)f2b((xb.y - mu) * rs * gb.y + bb.y);
          pk[6] = (short)f2b((xb.z - mu) * rs * gb.z + bb.z);
          pk[7] = (short)f2b((xb.w - mu) * rs * gb.w + bb.w);
          *(bf16x8*)&Alds[ck][rr][c8] = pk;
        } else {
          int m = row0 + rr;
          int t = m & 2047, b_ = m >> 11;
          int qt = t >> 4, r16 = t & 15;
          int hh = kk >> 6;
          int u0 = (((b_ * NH + hh) << 7) + qt) << 2;
          int je = ((qt * 16 + 15) / 17) * 17 + 17; je = je < TSEQ ? je : TSEQ;
          int nch = (je + CKV - 1) >> 9;
          float mm[4]; float mg = -1e30f;
          #pragma unroll
          for (int ch = 0; ch < 4; ++ch){
            mm[ch] = (ch < nch) ? pml[(size_t)(u0 + ch) * 32 + r16 * 2] : -1e30f;
            mg = fmaxf(mg, mm[ch]);
          }
          float aw[4]; float lg = 0.f;
          #pragma unroll
          for (int ch = 0; ch < 4; ++ch){
            float ll = (ch < nch) ? pml[(size_t)(u0 + ch) * 32 + r16 * 2 + 1] : 0.f;
            aw[ch] = (ch < nch) ? __expf(mm[ch] - mg) : 0.f;
            lg += aw[ch] * ll;
          }
          float inv = 1.f / lg;
          float av[8] = {0.f,0.f,0.f,0.f,0.f,0.f,0.f,0.f};
          #pragma unroll
          for (int ch = 0; ch < 4; ++ch){
            bf16x8 pv = *(const bf16x8*)(po + (size_t)(u0 + ch) * 1024 + r16 * 64 + c8);
            #pragma unroll
            for (int j = 0; j < 8; ++j) av[j] += aw[ch] * b2f((ushort)pv[j]);
          }
          bf16x8 pk;
          #pragma unroll
          for (int j = 0; j < 8; ++j) pk[j] = (short)f2b(av[j] * inv);
          *(bf16x8*)&Alds[ck][rr][c8] = pk;
        }
      }
      // ---- stage B (64 rows) ----
      #pragma unroll
      for (int it = 0; it < 2; ++it){
        int rr = r + it * 32;
        *(bf16x8*)&Blds[ck][rr][c8] = *(const bf16x8*)(Bt + (size_t)(col0 + rr) * K + kk + c8);
      }
    }
    __syncthreads();
    #pragma unroll
    for (int ck = 0; ck < 2; ++ck){
      #pragma unroll
      for (int ks = 0; ks < 2; ++ks){
        bf16x8 af[2], bfr[NC];
        #pragma unroll
        for (int i = 0; i < 2; ++i)
          af[i] = *(const bf16x8*)&Alds[ck][wr * 32 + i * 16 + l15][ks * 32 + l4 * 8];
        #pragma unroll
        for (int i = 0; i < NC; ++i)
          bfr[i] = *(const bf16x8*)&Blds[ck][wc * (16 * NC) + i * 16 + l15][ks * 32 + l4 * 8];
        #pragma unroll
        for (int mr = 0; mr < 2; ++mr)
          #pragma unroll
          for (int nc = 0; nc < NC; ++nc)
            acc[mr][nc] = __builtin_amdgcn_mfma_f32_16x16x32_bf16(af[mr], bfr[nc], acc[mr][nc], 0, 0, 0);
      }
    }
    __syncthreads();
  }

  float sr_[2][4], q2_[2][4];
  if (STATS){
    #pragma unroll
    for (int mr = 0; mr < 2; ++mr)
      #pragma unroll
      for (int rr = 0; rr < 4; ++rr){ sr_[mr][rr] = 0.f; q2_[mr][rr] = 0.f; }
  }
  #pragma unroll
  for (int mr = 0; mr < 2; ++mr){
    #pragma unroll
    for (int nc = 0; nc < NC; ++nc){
      #pragma unroll
      for (int rr = 0; rr < 4; ++rr){
        int m = row0 + wr * 32 + mr * 16 + l4 * 4 + rr;
        int n = col0 + wc * (16 * NC) + nc * 16 + l15;
        float v = acc[mr][nc][rr] + bias[n];
        if (EPI == 0){
          int b = m >> 11, t = m & 2047;
          int which = n >> 8, hn = n & 255, hh = hn >> 6, hd = hn & 63;
          if (which == 0)      o0[(((size_t)(b * NH + hh)) * TPAD + t) * HDIM + hd] = f2b(v * 0.125f);
          else if (which == 1) o1[(((size_t)(b * NH + hh)) * TPAD + t) * HDIM + hd] = f2b(v);
          else                 o2[(((size_t)(b * NH + hh)) * HDIM + hd) * TPAD + t] = f2b(v);
        } else if (EPI == 1){
          float xn = xres[(size_t)m * 256 + n] + v;
          xres[(size_t)m * 256 + n] = xn;
          if (STATS){ sr_[mr][rr] += xn; q2_[mr][rr] += xn * xn; }
        } else {
          float uu = 0.7978845608028654f * (v + 0.044715f * v * v * v);
          float e = __expf(2.f * uu);
          float th = 1.f - 2.f / (e + 1.f);
          o0[(size_t)m * N + n] = f2b(0.5f * v * (1.f + th));
        }
      }
    }
  }
  if (STATS){
    #pragma unroll
    for (int mr = 0; mr < 2; ++mr){
      #pragma unroll
      for (int rr = 0; rr < 4; ++rr){
        float s = sr_[mr][rr], q = q2_[mr][rr];
        #pragma unroll
        for (int off = 1; off < 16; off <<= 1){ s += __shfl_xor(s, off); q += __shfl_xor(q, off); }
        if (l15 == 0){
          int rl = wr * 32 + mr * 16 + l4 * 4 + rr;
          statLds[rl][wc][0] = s;
          statLds[rl][wc][1] = q;
        }
      }
    }
    __syncthreads();
    if (tid < BM){
      float ssum = 0.f, qsum = 0.f;
      #pragma unroll
      for (int g = 0; g < NW; ++g){ ssum += statLds[tid][g][0]; qsum += statLds[tid][g][1]; }
      float2 pr; pr.x = ssum; pr.y = qsum;
      ((float2*)pstat_out)[(size_t)(row0 + tid) * 4 + blockIdx.y] = pr;
    }
  }
}

// ---- split-KV flash attention: swapped-operand QK^T, per-lane softmax,
//      defer-max rescale (T13) + setprio around MFMA clusters (T5) ----
// block = (qg 64 q-rows, ch 512-KV chunk, bh); grid (32,4,8); 4 waves x 16 q each.
__global__ __launch_bounds__(256) void attn_tile_k(const ushort* __restrict__ qq, const ushort* __restrict__ kkk,
                                                   const ushort* __restrict__ vt,
                                                   ushort* __restrict__ po, float* __restrict__ pml){
  __shared__ ushort Klds[64][72];
  __shared__ ushort Vlds[64][72];
  __shared__ ushort Plds[4][16][72];
  int tid = threadIdx.x, w = tid >> 6, lane = tid & 63;
  int l15 = lane & 15, l4 = lane >> 4;
  int qg = blockIdx.x, ch = blockIdx.y, bh = blockIdx.z;
  int r0 = qg * 64;
  int je_blk = ((r0 + 63) / 17 + 1) * 17; je_blk = je_blk < TSEQ ? je_blk : TSEQ;
  int jstart = ch * CKV;
  if (jstart >= je_blk) return;                       // idle block (uniform)
  int jend = (jstart + CKV) < je_blk ? (jstart + CKV) : je_blk;

  int i0 = r0 + w * 16;
  int je_w = ((i0 + 15) / 17 + 1) * 17; je_w = je_w < TSEQ ? je_w : TSEQ;

  const ushort* qb = qq  + (size_t)bh * TPAD * HDIM;
  const ushort* kb = kkk + (size_t)bh * TPAD * HDIM;
  const ushort* vb = vt  + (size_t)bh * HDIM * TPAD;

  int ig = i0 + l15;                                  // this lane's query row
  int ibase = (int)((unsigned)ig / 17u) * 17;         // its block start
  bf16x8 aq0 = *(const bf16x8*)(qb + (size_t)ig * HDIM + l4 * 8);
  bf16x8 aq1 = *(const bf16x8*)(qb + (size_t)ig * HDIM + 32 + l4 * 8);

  f32x4 zero = {0.f, 0.f, 0.f, 0.f};
  float m_ = -1e30f, l_ = 0.f;
  f32x4 o_[4];
  o_[0] = zero; o_[1] = zero; o_[2] = zero; o_[3] = zero;

  int sr = tid >> 2, sc = (tid & 3) * 16;             // staging: 4 threads/row, 32B each
  for (int j0 = jstart; j0 < jend; j0 += 64){
    __syncthreads();
    *(bf16x8*)&Klds[sr][sc]     = *(const bf16x8*)(kb + (size_t)(j0 + sr) * HDIM + sc);
    *(bf16x8*)&Klds[sr][sc + 8] = *(const bf16x8*)(kb + (size_t)(j0 + sr) * HDIM + sc + 8);
    *(bf16x8*)&Vlds[sr][sc]     = *(const bf16x8*)(vb + (size_t)sr * TPAD + j0 + sc);
    *(bf16x8*)&Vlds[sr][sc + 8] = *(const bf16x8*)(vb + (size_t)sr * TPAD + j0 + sc + 8);
    __syncthreads();
    if (j0 >= je_w) continue;
    f32x4 s[4];
    __builtin_amdgcn_s_setprio(1);
    #pragma unroll
    for (int f = 0; f < 4; ++f){
      bf16x8 kf = *(const bf16x8*)&Klds[f * 16 + l15][l4 * 8];
      s[f] = __builtin_amdgcn_mfma_f32_16x16x32_bf16(kf, aq0, zero, 0, 0, 0);
    }
    #pragma unroll
    for (int f = 0; f < 4; ++f){
      bf16x8 kf = *(const bf16x8*)&Klds[f * 16 + l15][32 + l4 * 8];
      s[f] = __builtin_amdgcn_mfma_f32_16x16x32_bf16(kf, aq1, s[f], 0, 0, 0);
    }
    __builtin_amdgcn_s_setprio(0);
    if (j0 + 63 > i0){
      #pragma unroll
      for (int f = 0; f < 4; ++f){
        #pragma unroll
        for (int rr = 0; rr < 4; ++rr){
          int jg = j0 + f * 16 + l4 * 4 + rr;
          bool ok = (jg <= ig) || ((unsigned)(jg - ibase) < 17u);
          s[f][rr] = ok ? s[f][rr] : -1e30f;
        }
      }
    }
    float mf0 = fmaxf(fmaxf(s[0][0], s[0][1]), fmaxf(s[0][2], s[0][3]));
    float mf1 = fmaxf(fmaxf(s[1][0], s[1][1]), fmaxf(s[1][2], s[1][3]));
    float mf2 = fmaxf(fmaxf(s[2][0], s[2][1]), fmaxf(s[2][2], s[2][3]));
    float mf3 = fmaxf(fmaxf(s[3][0], s[3][1]), fmaxf(s[3][2], s[3][3]));
    float mx = fmaxf(fmaxf(mf0, mf1), fmaxf(mf2, mf3));
    mx = fmaxf(mx, __shfl_xor(mx, 16));
    mx = fmaxf(mx, __shfl_xor(mx, 32));
    // defer-max: skip O/l rescale when max growth is bounded (P <= e^8, bf16-safe)
    float mn = m_;
    if (!__all(mx - m_ <= 8.f)){
      mn = fmaxf(m_, mx);
      float alpha = __expf(m_ - mn);
      l_ *= alpha;
      #pragma unroll
      for (int f = 0; f < 4; ++f) o_[f] *= alpha;
      m_ = mn;
    }
    float ps = 0.f;
    #pragma unroll
    for (int f = 0; f < 4; ++f){
      bf16x4 pk;
      #pragma unroll
      for (int rr = 0; rr < 4; ++rr){
        float p = __expf(s[f][rr] - mn);
        ps += p;
        pk[rr] = (short)f2b(p);
      }
      *(bf16x4*)&Plds[w][l15][f * 16 + l4 * 4] = pk;
    }
    ps += __shfl_xor(ps, 16);
    ps += __shfl_xor(ps, 32);
    l_ += ps;
    __builtin_amdgcn_s_setprio(1);
    #pragma unroll
    for (int ks = 0; ks < 2; ++ks){
      bf16x8 pf = *(const bf16x8*)&Plds[w][l15][ks * 32 + l4 * 8];
      #pragma unroll
      for (int f = 0; f < 4; ++f){
        bf16x8 vf = *(const bf16x8*)&Vlds[f * 16 + l15][ks * 32 + l4 * 8];
        o_[f] = __builtin_amdgcn_mfma_f32_16x16x32_bf16(vf, pf, o_[f], 0, 0, 0);
      }
    }
    __builtin_amdgcn_s_setprio(0);
  }
  int qt = qg * 4 + w;
  int u = ((bh << 7) + qt) * 4 + ch;
  size_t ob = (size_t)u * 1024;
  #pragma unroll
  for (int f = 0; f < 4; ++f){
    bf16x4 pk;
    #pragma unroll
    for (int rr = 0; rr < 4; ++rr) pk[rr] = (short)f2b(o_[f][rr]);
    *(bf16x4*)&po[ob + (size_t)l15 * 64 + f * 16 + l4 * 4] = pk;
  }
  if (l4 == 0){
    pml[(size_t)u * 32 + l15 * 2 + 0] = m_;
    pml[(size_t)u * 32 + l15 * 2 + 1] = l_;
  }
}

extern "C" void kernel_launch(void* const* d_in, const int* in_sizes, int n_in,
                              void* d_out, int out_size, void* d_ws, size_t ws_size,
                              hipStream_t stream){
  const float* seq    = (const float*)d_in[0];
  const float* ln1_g  = (const float*)d_in[1];
  const float* ln1_b  = (const float*)d_in[2];
  const float* wq     = (const float*)d_in[3];
  const float* bq     = (const float*)d_in[4];
  const float* wk     = (const float*)d_in[5];
  const float* bk     = (const float*)d_in[6];
  const float* wv     = (const float*)d_in[7];
  const float* bv     = (const float*)d_in[8];
  const float* wproj  = (const float*)d_in[9];
  const float* bproj  = (const float*)d_in[10];
  const float* ln2_g  = (const float*)d_in[11];
  const float* ln2_b  = (const float*)d_in[12];
  const float* w1     = (const float*)d_in[13];
  const float* b1     = (const float*)d_in[14];
  const float* w2     = (const float*)d_in[15];
  const float* b2     = (const float*)d_in[16];
  const float* lnf_g  = (const float*)d_in[17];
  const float* lnf_b  = (const float*)d_in[18];

  size_t off = 0;
  char* base = (char*)d_ws;
  auto carve = [&](size_t bytes) -> void* {
    void* p = base + off;
    off += (bytes + 255) & ~(size_t)255;
    return p;
  };
  float*  x      = (float*) carve((size_t)MPAD * DMOD * 4);
  ushort* qbuf   = (ushort*)carve((size_t)BSZ * NH * TPAD * HDIM * 2);
  ushort* kbuf   = (ushort*)carve((size_t)BSZ * NH * TPAD * HDIM * 2);
  ushort* vtbuf  = (ushort*)carve((size_t)BSZ * NH * TPAD * HDIM * 2);
  ushort* mid    = (ushort*)carve((size_t)MPAD * DFF * 2);
  ushort* wqkvT  = (ushort*)carve((size_t)NL * 768 * 256 * 2);
  ushort* wprojT = (ushort*)carve((size_t)NL * 256 * 256 * 2);
  ushort* w1T    = (ushort*)carve((size_t)NL * 1024 * 256 * 2);
  ushort* w2T    = (ushort*)carve((size_t)NL * 256 * 1024 * 2);
  float*  bqkv   = (float*) carve((size_t)NL * 768 * 4);
  ushort* po     = (ushort*)carve((size_t)4096 * 1024 * 2);
  float*  pml    = (float*) carve((size_t)4096 * 32 * 4);
  float*  pstatA = (float*) carve((size_t)MPAD * 8 * 4);
  float*  pstatB = (float*) carve((size_t)MPAD * 8 * 4);
  if (off > ws_size) return;

  // prep
  copy_in_k<<<dim3(MPAD/4), dim3(256), 0, stream>>>(seq, x, pstatA);
  wtrans_k<<<dim3(4, 4, NL),  dim3(256), 0, stream>>>(wq,    wqkvT,  256, 256,  768, 0);
  wtrans_k<<<dim3(4, 4, NL),  dim3(256), 0, stream>>>(wk,    wqkvT,  256, 256,  768, 256);
  wtrans_k<<<dim3(4, 4, NL),  dim3(256), 0, stream>>>(wv,    wqkvT,  256, 256,  768, 512);
  wtrans_k<<<dim3(4, 4, NL),  dim3(256), 0, stream>>>(wproj, wprojT, 256, 256,  256, 0);
  wtrans_k<<<dim3(4, 16, NL), dim3(256), 0, stream>>>(w1,    w1T,   1024, 256, 1024, 0);
  wtrans_k<<<dim3(16, 4, NL), dim3(256), 0, stream>>>(w2,    w2T,    256,1024,  256, 0);
  bqkv_k<<<dim3((NL*768 + 255)/256), dim3(256), 0, stream>>>(bq, bk, bv, bqkv);

  for (int l = 0; l < NL; ++l){
    gemm_k<768,256,1,0,0,64><<<dim3(64,12), dim3(256), 0, stream>>>(
        nullptr, x, pstatA, ln1_g + l*256, ln1_b + l*256, nullptr, nullptr,
        wqkvT + (size_t)l*768*256, bqkv + l*768, nullptr, nullptr, qbuf, kbuf, vtbuf);
    attn_tile_k<<<dim3(32,4,8), dim3(256), 0, stream>>>(qbuf, kbuf, vtbuf, po, pml);
    gemm_k<256,256,2,1,1,32><<<dim3(128,4), dim3(256), 0, stream>>>(
        nullptr, nullptr, nullptr, nullptr, nullptr, po, pml,
        wprojT + (size_t)l*256*256, bproj + l*256, x, pstatB, nullptr, nullptr, nullptr);
    gemm_k<1024,256,1,2,0,64><<<dim3(64,16), dim3(256), 0, stream>>>(
        nullptr, x, pstatB, ln2_g + l*256, ln2_b + l*256, nullptr, nullptr,
        w1T + (size_t)l*1024*256, b1 + l*1024, nullptr, nullptr, mid, nullptr, nullptr);
    gemm_k<256,1024,0,1,1,32><<<dim3(128,4), dim3(256), 0, stream>>>(
        mid, nullptr, nullptr, nullptr, nullptr, nullptr, nullptr,
        w2T + (size_t)l*256*1024, b2 + l*256, x, pstatA, nullptr, nullptr, nullptr);
  }
  lnf_k<<<dim3(BSZ*TSEQ/4), dim3(256), 0, stream>>>(x, lnf_g, lnf_b, (float*)d_out);
}

// Round 21
// 639.325 us; speedup vs baseline: 1.1404x; 1.0219x over previous
//
#include <hip/hip_runtime.h>
#include <math.h>

#define NL 10
#define BSZ 2
#define TSEQ 2040
#define TPAD 2048
#define DMOD 256
#define NH 4
#define HDIM 64
#define DFF 1024
#define MPAD (BSZ*TPAD)   // 4096
#define CKV 512           // KV chunk per attention block

typedef __attribute__((ext_vector_type(8))) short bf16x8;
typedef __attribute__((ext_vector_type(4))) short bf16x4;
typedef __attribute__((ext_vector_type(4))) float f32x4;

__device__ __forceinline__ ushort f2b(float f){
  union { float f; unsigned u; } v; v.f = f;
  unsigned u = v.u;
  return (ushort)((u + 0x7FFFu + ((u >> 16) & 1u)) >> 16);
}
__device__ __forceinline__ float b2f(ushort h){
  union { unsigned u; float f; } v; v.u = ((unsigned)h) << 16; return v.f;
}

// ---- fused prep: weight transposes + qkv bias concat + input copy/stats ----
// grid.x = 2974: [0,1920) wtrans tiles, [1920,1950) bqkv, [1950,2974) copy_in.
__global__ __launch_bounds__(256) void prep_k(
    const float* __restrict__ seq, float* __restrict__ x, float* __restrict__ pstat,
    const float* __restrict__ wq, const float* __restrict__ wk, const float* __restrict__ wv,
    const float* __restrict__ wproj, const float* __restrict__ w1, const float* __restrict__ w2,
    ushort* __restrict__ wqkvT, ushort* __restrict__ wprojT,
    ushort* __restrict__ w1T, ushort* __restrict__ w2T,
    const float* __restrict__ bq, const float* __restrict__ bk, const float* __restrict__ bv,
    float* __restrict__ bqkv){
  __shared__ ushort tile[64][72];
  int bid = blockIdx.x, tid = threadIdx.x;
  if (bid < 1920){
    const float* src; ushort* dst; int N, K, NTOT, row0, kx, ny, l;
    if (bid < 640){
      int seg = bid / 160, idx = bid % 160;
      kx = idx & 3; ny = (idx >> 2) & 3; l = idx >> 4;
      K = 256; N = 256;
      if (seg == 0){ src = wq;    dst = wqkvT;  NTOT = 768; row0 = 0;   }
      else if (seg == 1){ src = wk; dst = wqkvT; NTOT = 768; row0 = 256; }
      else if (seg == 2){ src = wv; dst = wqkvT; NTOT = 768; row0 = 512; }
      else { src = wproj; dst = wprojT; NTOT = 256; row0 = 0; }
    } else if (bid < 1280){
      int idx = bid - 640;
      kx = idx & 3; ny = (idx >> 2) & 15; l = idx >> 6;
      src = w1; dst = w1T; N = 1024; K = 256; NTOT = 1024; row0 = 0;
    } else {
      int idx = bid - 1280;
      kx = idx & 15; ny = (idx >> 4) & 3; l = idx >> 6;
      src = w2; dst = w2T; N = 256; K = 1024; NTOT = 256; row0 = 0;
    }
    int kk0 = kx * 64, n0 = ny * 64;
    int kl = tid >> 2, nq = tid & 3;
    const float* sp = src + ((size_t)(l * K + kk0 + kl)) * N + n0 + nq * 16;
    #pragma unroll
    for (int i = 0; i < 4; ++i){
      float4 v = ((const float4*)sp)[i];
      int nb = nq * 16 + i * 4;
      tile[nb + 0][kl] = f2b(v.x);
      tile[nb + 1][kl] = f2b(v.y);
      tile[nb + 2][kl] = f2b(v.z);
      tile[nb + 3][kl] = f2b(v.w);
    }
    __syncthreads();
    int r = tid >> 2, cq = (tid & 3) * 16;
    ushort* dp = dst + ((size_t)(l * NTOT + row0 + n0 + r)) * K + kk0 + cq;
    *(bf16x8*)dp       = *(const bf16x8*)&tile[r][cq];
    *(bf16x8*)(dp + 8) = *(const bf16x8*)&tile[r][cq + 8];
  } else if (bid < 1950){
    int idx = (bid - 1920) * 256 + tid;
    if (idx < NL * 768){
      int l = idx / 768, n = idx % 768;
      float v = (n < 256) ? bq[l * 256 + n] : ((n < 512) ? bk[l * 256 + n - 256] : bv[l * 256 + n - 512]);
      bqkv[idx] = v;
    }
  } else {
    int idx = (bid - 1950) * 256 + tid;
    int row = idx >> 6, c = idx & 63;
    int b = row >> 11, t = row & 2047;
    float4 v = {0.f, 0.f, 0.f, 0.f};
    if (t < TSEQ) v = ((const float4*)(seq + ((size_t)(b * TSEQ + t)) * DMOD))[c];
    ((float4*)(x + (size_t)row * DMOD))[c] = v;
    float s  = v.x + v.y + v.z + v.w;
    float s2 = v.x*v.x + v.y*v.y + v.z*v.z + v.w*v.w;
    #pragma unroll
    for (int off = 1; off < 16; off <<= 1){ s += __shfl_xor(s, off); s2 += __shfl_xor(s2, off); }
    if ((c & 15) == 0){
      float2 pr; pr.x = s; pr.y = s2;
      ((float2*)pstat)[(size_t)row * 4 + (c >> 4)] = pr;
    }
  }
}

// ---- final layernorm -> f32 d_out (compact rows); 4 rows per block ----
__global__ __launch_bounds__(256) void lnf_k(const float* __restrict__ x, const float* __restrict__ g,
                                             const float* __restrict__ be, float* __restrict__ outf){
  int tid = threadIdx.x;
  int row = blockIdx.x * 4 + (tid >> 6), lane = tid & 63;
  int b = row / TSEQ, t = row % TSEQ;
  int irow = b * TPAD + t;
  float4 xv = ((const float4*)(x + (size_t)irow * DMOD))[lane];
  float s  = xv.x + xv.y + xv.z + xv.w;
  float s2 = xv.x*xv.x + xv.y*xv.y + xv.z*xv.z + xv.w*xv.w;
  #pragma unroll
  for (int off = 1; off < 64; off <<= 1){ s += __shfl_xor(s, off); s2 += __shfl_xor(s2, off); }
  float mu = s * (1.f/256.f);
  float var = s2 * (1.f/256.f) - mu * mu;
  float rs = rsqrtf(var + 1e-5f);
  float4 gv = ((const float4*)g)[lane];
  float4 bv = ((const float4*)be)[lane];
  float4 ov;
  ov.x = (xv.x - mu) * rs * gv.x + bv.x;
  ov.y = (xv.y - mu) * rs * gv.y + bv.y;
  ov.z = (xv.z - mu) * rs * gv.z + bv.z;
  ov.w = (xv.w - mu) * rs * gv.w + bv.w;
  ((float4*)(outf + (size_t)row * DMOD))[lane] = ov;
}

// ---- BMx64-tile GEMM, BK=128 ----
// BM=64: 4 waves as 2x2 (32x32 each). BM=32: 4 waves as 1x4 (32x16 each).
// AMODE 0: A = Ab; AMODE 1: A = LN(Af) via pstat_in; AMODE 2: A = merged attn
// EPI 0: QKV scatter (q pre-scaled; v [b,h,hd,t]); EPI 1: xres += v; EPI 2: GELU -> o0
// STATS 1: per-(row, colblock64) partial {sum,sumsq} of x_new -> pstat_out
template<int N, int K, int AMODE, int EPI, int STATS, int BM>
__global__ __launch_bounds__(256) void gemm_k(
    const ushort* __restrict__ Ab, const float* __restrict__ Af,
    const float* __restrict__ pstat_in, const float* __restrict__ lng, const float* __restrict__ lnb,
    const ushort* __restrict__ po, const float* __restrict__ pml,
    const ushort* __restrict__ Bt, const float* __restrict__ bias,
    float* __restrict__ xres, float* __restrict__ pstat_out,
    ushort* __restrict__ o0, ushort* __restrict__ o1, ushort* __restrict__ o2){
  constexpr int NC = (BM == 64) ? 2 : 1;      // col fragments per wave
  constexpr int NW = (BM == 64) ? 2 : 4;      // col groups (waves in col dim)
  __shared__ ushort Alds[2][BM][72];
  __shared__ ushort Blds[2][64][72];
  __shared__ float statLds[STATS ? BM : 1][NW][2];
  int tid = threadIdx.x;
  int w = tid >> 6, lane = tid & 63;
  int wr = (BM == 64) ? (w >> 1) : 0;
  int wc = (BM == 64) ? (w & 1) : w;
  int l15 = lane & 15, l4 = lane >> 4;
  int row0 = blockIdx.x * BM, col0 = blockIdx.y * 64;
  int r = tid >> 3, c8 = (tid & 7) * 8;       // r in [0,32)

  float muA = 0.f, rsA = 0.f, muB = 0.f, rsB = 0.f;
  if (AMODE == 1){
    const float4* pa = (const float4*)(pstat_in + (size_t)(row0 + r) * 8);
    float4 a0 = pa[0], a1 = pa[1];
    float s = a0.x + a0.z + a1.x + a1.z, q = a0.y + a0.w + a1.y + a1.w;
    muA = s * (1.f/256.f);
    rsA = rsqrtf(q * (1.f/256.f) - muA * muA + 1e-5f);
    if (BM == 64){
      const float4* pb = (const float4*)(pstat_in + (size_t)(row0 + r + 32) * 8);
      float4 b0 = pb[0], b1 = pb[1];
      s = b0.x + b0.z + b1.x + b1.z; q = b0.y + b0.w + b1.y + b1.w;
      muB = s * (1.f/256.f);
      rsB = rsqrtf(q * (1.f/256.f) - muB * muB + 1e-5f);
    }
  }

  f32x4 zero = {0.f, 0.f, 0.f, 0.f};
  f32x4 acc[2][NC];
  #pragma unroll
  for (int mr = 0; mr < 2; ++mr)
    #pragma unroll
    for (int nc = 0; nc < NC; ++nc) acc[mr][nc] = zero;

  for (int k0 = 0; k0 < K; k0 += 128){
    #pragma unroll
    for (int ck = 0; ck < 2; ++ck){
      int kk = k0 + ck * 64;
      // ---- stage A (BM rows) ----
      #pragma unroll
      for (int it = 0; it < BM / 32; ++it){
        int rr = r + it * 32;
        if (AMODE == 0){
          *(bf16x8*)&Alds[ck][rr][c8] = *(const bf16x8*)(Ab + (size_t)(row0 + rr) * K + kk + c8);
        } else if (AMODE == 1){
          float mu = it ? muB : muA, rs = it ? rsB : rsA;
          const float4* xp = (const float4*)(Af + (size_t)(row0 + rr) * 256 + kk + c8);
          float4 xa = xp[0], xb = xp[1];
          const float4* gp = (const float4*)(lng + kk + c8);
          const float4* bp = (const float4*)(lnb + kk + c8);
          float4 ga = gp[0], gb = gp[1], ba = bp[0], bb = bp[1];
          bf16x8 pk;
          pk[0] = (short)f2b((xa.x - mu) * rs * ga.x + ba.x);
          pk[1] = (short)f2b((xa.y - mu) * rs * ga.y + ba.y);
          pk[2] = (short)f2b((xa.z - mu) * rs * ga.z + ba.z);
          pk[3] = (short)f2b((xa.w - mu) * rs * ga.w + ba.w);
          pk[4] = (short)f2b((xb.x - mu) * rs * gb.x + bb.x);
          pk[5] = (short)f2b((xb.y - mu) * rs * gb.y + bb.y);
          pk[6] = (short)f2b((xb.z - mu) * rs * gb.z + bb.z);
          pk[7] = (short)f2b((xb.w - mu) * rs * gb.w + bb.w);
          *(bf16x8*)&Alds[ck][rr][c8] = pk;
        } else {
          int m = row0 + rr;
          int t = m & 2047, b_ = m >> 11;
          int qt = t >> 4, r16 = t & 15;
          int hh = kk >> 6;
          int u0 = (((b_ * NH + hh) << 7) + qt) << 2;
          int je = ((qt * 16 + 15) / 17) * 17 + 17; je = je < TSEQ ? je : TSEQ;
          int nch = (je + CKV - 1) >> 9;
          float mm[4]; float mg = -1e30f;
          #pragma unroll
          for (int ch = 0; ch < 4; ++ch){
            mm[ch] = (ch < nch) ? pml[(size_t)(u0 + ch) * 32 + r16 * 2] : -1e30f;
            mg = fmaxf(mg, mm[ch]);
          }
          float aw[4]; float lg = 0.f;
          #pragma unroll
          for (int ch = 0; ch < 4; ++ch){
            float ll = (ch < nch) ? pml[(size_t)(u0 + ch) * 32 + r16 * 2 + 1] : 0.f;
            aw[ch] = (ch < nch) ? __expf(mm[ch] - mg) : 0.f;
            lg += aw[ch] * ll;
          }
          float inv = 1.f / lg;
          float av[8] = {0.f,0.f,0.f,0.f,0.f,0.f,0.f,0.f};
          #pragma unroll
          for (int ch = 0; ch < 4; ++ch){
            bf16x8 pv = *(const bf16x8*)(po + (size_t)(u0 + ch) * 1024 + r16 * 64 + c8);
            #pragma unroll
            for (int j = 0; j < 8; ++j) av[j] += aw[ch] * b2f((ushort)pv[j]);
          }
          bf16x8 pk;
          #pragma unroll
          for (int j = 0; j < 8; ++j) pk[j] = (short)f2b(av[j] * inv);
          *(bf16x8*)&Alds[ck][rr][c8] = pk;
        }
      }
      // ---- stage B (64 rows) ----
      #pragma unroll
      for (int it = 0; it < 2; ++it){
        int rr = r + it * 32;
        *(bf16x8*)&Blds[ck][rr][c8] = *(const bf16x8*)(Bt + (size_t)(col0 + rr) * K + kk + c8);
      }
    }
    __syncthreads();
    #pragma unroll
    for (int ck = 0; ck < 2; ++ck){
      #pragma unroll
      for (int ks = 0; ks < 2; ++ks){
        bf16x8 af[2], bfr[NC];
        #pragma unroll
        for (int i = 0; i < 2; ++i)
          af[i] = *(const bf16x8*)&Alds[ck][wr * 32 + i * 16 + l15][ks * 32 + l4 * 8];
        #pragma unroll
        for (int i = 0; i < NC; ++i)
          bfr[i] = *(const bf16x8*)&Blds[ck][wc * (16 * NC) + i * 16 + l15][ks * 32 + l4 * 8];
        #pragma unroll
        for (int mr = 0; mr < 2; ++mr)
          #pragma unroll
          for (int nc = 0; nc < NC; ++nc)
            acc[mr][nc] = __builtin_amdgcn_mfma_f32_16x16x32_bf16(af[mr], bfr[nc], acc[mr][nc], 0, 0, 0);
      }
    }
    __syncthreads();
  }

  float sr_[2][4], q2_[2][4];
  if (STATS){
    #pragma unroll
    for (int mr = 0; mr < 2; ++mr)
      #pragma unroll
      for (int rr = 0; rr < 4; ++rr){ sr_[mr][rr] = 0.f; q2_[mr][rr] = 0.f; }
  }
  #pragma unroll
  for (int mr = 0; mr < 2; ++mr){
    #pragma unroll
    for (int nc = 0; nc < NC; ++nc){
      #pragma unroll
      for (int rr = 0; rr < 4; ++rr){
        int m = row0 + wr * 32 + mr * 16 + l4 * 4 + rr;
        int n = col0 + wc * (16 * NC) + nc * 16 + l15;
        float v = acc[mr][nc][rr] + bias[n];
        if (EPI == 0){
          int b = m >> 11, t = m & 2047;
          int which = n >> 8, hn = n & 255, hh = hn >> 6, hd = hn & 63;
          if (which == 0)      o0[(((size_t)(b * NH + hh)) * TPAD + t) * HDIM + hd] = f2b(v * 0.125f);
          else if (which == 1) o1[(((size_t)(b * NH + hh)) * TPAD + t) * HDIM + hd] = f2b(v);
          else                 o2[(((size_t)(b * NH + hh)) * HDIM + hd) * TPAD + t] = f2b(v);
        } else if (EPI == 1){
          float xn = xres[(size_t)m * 256 + n] + v;
          xres[(size_t)m * 256 + n] = xn;
          if (STATS){ sr_[mr][rr] += xn; q2_[mr][rr] += xn * xn; }
        } else {
          float uu = 0.7978845608028654f * (v + 0.044715f * v * v * v);
          float e = __expf(2.f * uu);
          float th = 1.f - 2.f / (e + 1.f);
          o0[(size_t)m * N + n] = f2b(0.5f * v * (1.f + th));
        }
      }
    }
  }
  if (STATS){
    #pragma unroll
    for (int mr = 0; mr < 2; ++mr){
      #pragma unroll
      for (int rr = 0; rr < 4; ++rr){
        float s = sr_[mr][rr], q = q2_[mr][rr];
        #pragma unroll
        for (int off = 1; off < 16; off <<= 1){ s += __shfl_xor(s, off); q += __shfl_xor(q, off); }
        if (l15 == 0){
          int rl = wr * 32 + mr * 16 + l4 * 4 + rr;
          statLds[rl][wc][0] = s;
          statLds[rl][wc][1] = q;
        }
      }
    }
    __syncthreads();
    if (tid < BM){
      float ssum = 0.f, qsum = 0.f;
      #pragma unroll
      for (int g = 0; g < NW; ++g){ ssum += statLds[tid][g][0]; qsum += statLds[tid][g][1]; }
      float2 pr; pr.x = ssum; pr.y = qsum;
      ((float2*)pstat_out)[(size_t)(row0 + tid) * 4 + blockIdx.y] = pr;
    }
  }
}

// ---- split-KV flash attention: swapped-operand QK^T, per-lane softmax,
//      defer-max rescale (T13) + setprio around MFMA clusters (T5) ----
// block = (qg 64 q-rows, ch 512-KV chunk, bh); grid (32,4,8); 4 waves x 16 q each.
__global__ __launch_bounds__(256) void attn_tile_k(const ushort* __restrict__ qq, const ushort* __restrict__ kkk,
                                                   const ushort* __restrict__ vt,
                                                   ushort* __restrict__ po, float* __restrict__ pml){
  __shared__ ushort Klds[64][72];
  __shared__ ushort Vlds[64][72];
  __shared__ ushort Plds[4][16][72];
  int tid = threadIdx.x, w = tid >> 6, lane = tid & 63;
  int l15 = lane & 15, l4 = lane >> 4;
  int qg = blockIdx.x, ch = blockIdx.y, bh = blockIdx.z;
  int r0 = qg * 64;
  int je_blk = ((r0 + 63) / 17 + 1) * 17; je_blk = je_blk < TSEQ ? je_blk : TSEQ;
  int jstart = ch * CKV;
  if (jstart >= je_blk) return;                       // idle block (uniform)
  int jend = (jstart + CKV) < je_blk ? (jstart + CKV) : je_blk;

  int i0 = r0 + w * 16;
  int je_w = ((i0 + 15) / 17 + 1) * 17; je_w = je_w < TSEQ ? je_w : TSEQ;

  const ushort* qb = qq  + (size_t)bh * TPAD * HDIM;
  const ushort* kb = kkk + (size_t)bh * TPAD * HDIM;
  const ushort* vb = vt  + (size_t)bh * HDIM * TPAD;

  int ig = i0 + l15;                                  // this lane's query row
  int ibase = (int)((unsigned)ig / 17u) * 17;         // its block start
  bf16x8 aq0 = *(const bf16x8*)(qb + (size_t)ig * HDIM + l4 * 8);
  bf16x8 aq1 = *(const bf16x8*)(qb + (size_t)ig * HDIM + 32 + l4 * 8);

  f32x4 zero = {0.f, 0.f, 0.f, 0.f};
  float m_ = -1e30f, l_ = 0.f;
  f32x4 o_[4];
  o_[0] = zero; o_[1] = zero; o_[2] = zero; o_[3] = zero;

  int sr = tid >> 2, sc = (tid & 3) * 16;             // staging: 4 threads/row, 32B each
  for (int j0 = jstart; j0 < jend; j0 += 64){
    __syncthreads();
    *(bf16x8*)&Klds[sr][sc]     = *(const bf16x8*)(kb + (size_t)(j0 + sr) * HDIM + sc);
    *(bf16x8*)&Klds[sr][sc + 8] = *(const bf16x8*)(kb + (size_t)(j0 + sr) * HDIM + sc + 8);
    *(bf16x8*)&Vlds[sr][sc]     = *(const bf16x8*)(vb + (size_t)sr * TPAD + j0 + sc);
    *(bf16x8*)&Vlds[sr][sc + 8] = *(const bf16x8*)(vb + (size_t)sr * TPAD + j0 + sc + 8);
    __syncthreads();
    if (j0 >= je_w) continue;
    f32x4 s[4];
    __builtin_amdgcn_s_setprio(1);
    #pragma unroll
    for (int f = 0; f < 4; ++f){
      bf16x8 kf = *(const bf16x8*)&Klds[f * 16 + l15][l4 * 8];
      s[f] = __builtin_amdgcn_mfma_f32_16x16x32_bf16(kf, aq0, zero, 0, 0, 0);
    }
    #pragma unroll
    for (int f = 0; f < 4; ++f){
      bf16x8 kf = *(const bf16x8*)&Klds[f * 16 + l15][32 + l4 * 8];
      s[f] = __builtin_amdgcn_mfma_f32_16x16x32_bf16(kf, aq1, s[f], 0, 0, 0);
    }
    __builtin_amdgcn_s_setprio(0);
    if (j0 + 63 > i0){
      #pragma unroll
      for (int f = 0; f < 4; ++f){
        #pragma unroll
        for (int rr = 0; rr < 4; ++rr){
          int jg = j0 + f * 16 + l4 * 4 + rr;
          bool ok = (jg <= ig) || ((unsigned)(jg - ibase) < 17u);
          s[f][rr] = ok ? s[f][rr] : -1e30f;
        }
      }
    }
    float mf0 = fmaxf(fmaxf(s[0][0], s[0][1]), fmaxf(s[0][2], s[0][3]));
    float mf1 = fmaxf(fmaxf(s[1][0], s[1][1]), fmaxf(s[1][2], s[1][3]));
    float mf2 = fmaxf(fmaxf(s[2][0], s[2][1]), fmaxf(s[2][2], s[2][3]));
    float mf3 = fmaxf(fmaxf(s[3][0], s[3][1]), fmaxf(s[3][2], s[3][3]));
    float mx = fmaxf(fmaxf(mf0, mf1), fmaxf(mf2, mf3));
    mx = fmaxf(mx, __shfl_xor(mx, 16));
    mx = fmaxf(mx, __shfl_xor(mx, 32));
    // defer-max: skip O/l rescale when max growth is bounded (P <= e^8, bf16-safe)
    float mn = m_;
    if (!__all(mx - m_ <= 8.f)){
      mn = fmaxf(m_, mx);
      float alpha = __expf(m_ - mn);
      l_ *= alpha;
      #pragma unroll
      for (int f = 0; f < 4; ++f) o_[f] *= alpha;
      m_ = mn;
    }
    float ps = 0.f;
    #pragma unroll
    for (int f = 0; f < 4; ++f){
      bf16x4 pk;
      #pragma unroll
      for (int rr = 0; rr < 4; ++rr){
        float p = __expf(s[f][rr] - mn);
        ps += p;
        pk[rr] = (short)f2b(p);
      }
      *(bf16x4*)&Plds[w][l15][f * 16 + l4 * 4] = pk;
    }
    ps += __shfl_xor(ps, 16);
    ps += __shfl_xor(ps, 32);
    l_ += ps;
    __builtin_amdgcn_s_setprio(1);
    #pragma unroll
    for (int ks = 0; ks < 2; ++ks){
      bf16x8 pf = *(const bf16x8*)&Plds[w][l15][ks * 32 + l4 * 8];
      #pragma unroll
      for (int f = 0; f < 4; ++f){
        bf16x8 vf = *(const bf16x8*)&Vlds[f * 16 + l15][ks * 32 + l4 * 8];
        o_[f] = __builtin_amdgcn_mfma_f32_16x16x32_bf16(vf, pf, o_[f], 0, 0, 0);
      }
    }
    __builtin_amdgcn_s_setprio(0);
  }
  int qt = qg * 4 + w;
  int u = ((bh << 7) + qt) * 4 + ch;
  size_t ob = (size_t)u * 1024;
  #pragma unroll
  for (int f = 0; f < 4; ++f){
    bf16x4 pk;
    #pragma unroll
    for (int rr = 0; rr < 4; ++rr) pk[rr] = (short)f2b(o_[f][rr]);
    *(bf16x4*)&po[ob + (size_t)l15 * 64 + f * 16 + l4 * 4] = pk;
  }
  if (l4 == 0){
    pml[(size_t)u * 32 + l15 * 2 + 0] = m_;
    pml[(size_t)u * 32 + l15 * 2 + 1] = l_;
  }
}

extern "C" void kernel_launch(void* const* d_in, const int* in_sizes, int n_in,
                              void* d_out, int out_size, void* d_ws, size_t ws_size,
                              hipStream_t stream){
  const float* seq    = (const float*)d_in[0];
  const float* ln1_g  = (const float*)d_in[1];
  const float* ln1_b  = (const float*)d_in[2];
  const float* wq     = (const float*)d_in[3];
  const float* bq     = (const float*)d_in[4];
  const float* wk     = (const float*)d_in[5];
  const float* bk     = (const float*)d_in[6];
  const float* wv     = (const float*)d_in[7];
  const float* bv     = (const float*)d_in[8];
  const float* wproj  = (const float*)d_in[9];
  const float* bproj  = (const float*)d_in[10];
  const float* ln2_g  = (const float*)d_in[11];
  const float* ln2_b  = (const float*)d_in[12];
  const float* w1     = (const float*)d_in[13];
  const float* b1     = (const float*)d_in[14];
  const float* w2     = (const float*)d_in[15];
  const float* b2     = (const float*)d_in[16];
  const float* lnf_g  = (const float*)d_in[17];
  const float* lnf_b  = (const float*)d_in[18];

  size_t off = 0;
  char* base = (char*)d_ws;
  auto carve = [&](size_t bytes) -> void* {
    void* p = base + off;
    off += (bytes + 255) & ~(size_t)255;
    return p;
  };
  float*  x      = (float*) carve((size_t)MPAD * DMOD * 4);
  ushort* qbuf   = (ushort*)carve((size_t)BSZ * NH * TPAD * HDIM * 2);
  ushort* kbuf   = (ushort*)carve((size_t)BSZ * NH * TPAD * HDIM * 2);
  ushort* vtbuf  = (ushort*)carve((size_t)BSZ * NH * TPAD * HDIM * 2);
  ushort* mid    = (ushort*)carve((size_t)MPAD * DFF * 2);
  ushort* wqkvT  = (ushort*)carve((size_t)NL * 768 * 256 * 2);
  ushort* wprojT = (ushort*)carve((size_t)NL * 256 * 256 * 2);
  ushort* w1T    = (ushort*)carve((size_t)NL * 1024 * 256 * 2);
  ushort* w2T    = (ushort*)carve((size_t)NL * 256 * 1024 * 2);
  float*  bqkv   = (float*) carve((size_t)NL * 768 * 4);
  ushort* po     = (ushort*)carve((size_t)4096 * 1024 * 2);
  float*  pml    = (float*) carve((size_t)4096 * 32 * 4);
  float*  pstatA = (float*) carve((size_t)MPAD * 8 * 4);
  float*  pstatB = (float*) carve((size_t)MPAD * 8 * 4);
  if (off > ws_size) return;

  // fused prep: all transposes + bias concat + input copy/stats in ONE dispatch
  prep_k<<<dim3(2974), dim3(256), 0, stream>>>(
      seq, x, pstatA, wq, wk, wv, wproj, w1, w2,
      wqkvT, wprojT, w1T, w2T, bq, bk, bv, bqkv);

  for (int l = 0; l < NL; ++l){
    gemm_k<768,256,1,0,0,64><<<dim3(64,12), dim3(256), 0, stream>>>(
        nullptr, x, pstatA, ln1_g + l*256, ln1_b + l*256, nullptr, nullptr,
        wqkvT + (size_t)l*768*256, bqkv + l*768, nullptr, nullptr, qbuf, kbuf, vtbuf);
    attn_tile_k<<<dim3(32,4,8), dim3(256), 0, stream>>>(qbuf, kbuf, vtbuf, po, pml);
    gemm_k<256,256,2,1,1,32><<<dim3(128,4), dim3(256), 0, stream>>>(
        nullptr, nullptr, nullptr, nullptr, nullptr, po, pml,
        wprojT + (size_t)l*256*256, bproj + l*256, x, pstatB, nullptr, nullptr, nullptr);
    gemm_k<1024,256,1,2,0,64><<<dim3(64,16), dim3(256), 0, stream>>>(
        nullptr, x, pstatB, ln2_g + l*256, ln2_b + l*256, nullptr, nullptr,
        w1T + (size_t)l*1024*256, b1 + l*1024, nullptr, nullptr, mid, nullptr, nullptr);
    gemm_k<256,1024,0,1,1,32><<<dim3(128,4), dim3(256), 0, stream>>>(
        mid, nullptr, nullptr, nullptr, nullptr, nullptr, nullptr,
        w2T + (size_t)l*256*1024, b2 + l*256, x, pstatA, nullptr, nullptr, nullptr);
  }
  lnf_k<<<dim3(BSZ*TSEQ/4), dim3(256), 0, stream>>>(x, lnf_g, lnf_b, (float*)d_out);
}

// Round 22
// 637.909 us; speedup vs baseline: 1.1429x; 1.0022x over previous
//
#include <hip/hip_runtime.h>
#include <math.h>

#define NL 10
#define BSZ 2
#define TSEQ 2040
#define TPAD 2048
#define DMOD 256
#define NH 4
#define HDIM 64
#define DFF 1024
#define MPAD (BSZ*TPAD)   // 4096
#define CKV 512           // KV chunk per attention block

typedef __attribute__((ext_vector_type(8))) short bf16x8;
typedef __attribute__((ext_vector_type(4))) short bf16x4;
typedef __attribute__((ext_vector_type(4))) float f32x4;

__device__ __forceinline__ ushort f2b(float f){
  union { float f; unsigned u; } v; v.f = f;
  unsigned u = v.u;
  return (ushort)((u + 0x7FFFu + ((u >> 16) & 1u)) >> 16);
}
__device__ __forceinline__ float b2f(ushort h){
  union { unsigned u; float f; } v; v.u = ((unsigned)h) << 16; return v.f;
}

// ---- fused prep: weight transposes + qkv bias concat + input copy/stats ----
// grid.x = 2974: [0,1920) wtrans tiles, [1920,1950) bqkv, [1950,2974) copy_in.
__global__ __launch_bounds__(256) void prep_k(
    const float* __restrict__ seq, float* __restrict__ x, float* __restrict__ pstat,
    const float* __restrict__ wq, const float* __restrict__ wk, const float* __restrict__ wv,
    const float* __restrict__ wproj, const float* __restrict__ w1, const float* __restrict__ w2,
    ushort* __restrict__ wqkvT, ushort* __restrict__ wprojT,
    ushort* __restrict__ w1T, ushort* __restrict__ w2T,
    const float* __restrict__ bq, const float* __restrict__ bk, const float* __restrict__ bv,
    float* __restrict__ bqkv){
  __shared__ ushort tile[64][72];
  int bid = blockIdx.x, tid = threadIdx.x;
  if (bid < 1920){
    const float* src; ushort* dst; int N, K, NTOT, row0, kx, ny, l;
    if (bid < 640){
      int seg = bid / 160, idx = bid % 160;
      kx = idx & 3; ny = (idx >> 2) & 3; l = idx >> 4;
      K = 256; N = 256;
      if (seg == 0){ src = wq;    dst = wqkvT;  NTOT = 768; row0 = 0;   }
      else if (seg == 1){ src = wk; dst = wqkvT; NTOT = 768; row0 = 256; }
      else if (seg == 2){ src = wv; dst = wqkvT; NTOT = 768; row0 = 512; }
      else { src = wproj; dst = wprojT; NTOT = 256; row0 = 0; }
    } else if (bid < 1280){
      int idx = bid - 640;
      kx = idx & 3; ny = (idx >> 2) & 15; l = idx >> 6;
      src = w1; dst = w1T; N = 1024; K = 256; NTOT = 1024; row0 = 0;
    } else {
      int idx = bid - 1280;
      kx = idx & 15; ny = (idx >> 4) & 3; l = idx >> 6;
      src = w2; dst = w2T; N = 256; K = 1024; NTOT = 256; row0 = 0;
    }
    int kk0 = kx * 64, n0 = ny * 64;
    int kl = tid >> 2, nq = tid & 3;
    const float* sp = src + ((size_t)(l * K + kk0 + kl)) * N + n0 + nq * 16;
    #pragma unroll
    for (int i = 0; i < 4; ++i){
      float4 v = ((const float4*)sp)[i];
      int nb = nq * 16 + i * 4;
      tile[nb + 0][kl] = f2b(v.x);
      tile[nb + 1][kl] = f2b(v.y);
      tile[nb + 2][kl] = f2b(v.z);
      tile[nb + 3][kl] = f2b(v.w);
    }
    __syncthreads();
    int r = tid >> 2, cq = (tid & 3) * 16;
    ushort* dp = dst + ((size_t)(l * NTOT + row0 + n0 + r)) * K + kk0 + cq;
    *(bf16x8*)dp       = *(const bf16x8*)&tile[r][cq];
    *(bf16x8*)(dp + 8) = *(const bf16x8*)&tile[r][cq + 8];
  } else if (bid < 1950){
    int idx = (bid - 1920) * 256 + tid;
    if (idx < NL * 768){
      int l = idx / 768, n = idx % 768;
      float v = (n < 256) ? bq[l * 256 + n] : ((n < 512) ? bk[l * 256 + n - 256] : bv[l * 256 + n - 512]);
      bqkv[idx] = v;
    }
  } else {
    int idx = (bid - 1950) * 256 + tid;
    int row = idx >> 6, c = idx & 63;
    int b = row >> 11, t = row & 2047;
    float4 v = {0.f, 0.f, 0.f, 0.f};
    if (t < TSEQ) v = ((const float4*)(seq + ((size_t)(b * TSEQ + t)) * DMOD))[c];
    ((float4*)(x + (size_t)row * DMOD))[c] = v;
    float s  = v.x + v.y + v.z + v.w;
    float s2 = v.x*v.x + v.y*v.y + v.z*v.z + v.w*v.w;
    #pragma unroll
    for (int off = 1; off < 16; off <<= 1){ s += __shfl_xor(s, off); s2 += __shfl_xor(s2, off); }
    if ((c & 15) == 0){
      float2 pr; pr.x = s; pr.y = s2;
      ((float2*)pstat)[(size_t)row * 4 + (c >> 4)] = pr;
    }
  }
}

// ---- final layernorm -> f32 d_out; row stats from pstat (mlp2 STATS chain) ----
__global__ __launch_bounds__(256) void lnf_k(const float* __restrict__ x, const float* __restrict__ pstat,
                                             const float* __restrict__ g, const float* __restrict__ be,
                                             float* __restrict__ outf){
  int tid = threadIdx.x;
  int row = blockIdx.x * 4 + (tid >> 6), lane = tid & 63;
  int b = row / TSEQ, t = row % TSEQ;
  int irow = b * TPAD + t;
  const float4* pa = (const float4*)(pstat + (size_t)irow * 8);
  float4 a0 = pa[0], a1 = pa[1];
  float s = a0.x + a0.z + a1.x + a1.z;
  float q = a0.y + a0.w + a1.y + a1.w;
  float mu = s * (1.f/256.f);
  float var = q * (1.f/256.f) - mu * mu;
  float rs = rsqrtf(var + 1e-5f);
  float4 xv = ((const float4*)(x + (size_t)irow * DMOD))[lane];
  float4 gv = ((const float4*)g)[lane];
  float4 bv = ((const float4*)be)[lane];
  float4 ov;
  ov.x = (xv.x - mu) * rs * gv.x + bv.x;
  ov.y = (xv.y - mu) * rs * gv.y + bv.y;
  ov.z = (xv.z - mu) * rs * gv.z + bv.z;
  ov.w = (xv.w - mu) * rs * gv.w + bv.w;
  ((float4*)(outf + (size_t)row * DMOD))[lane] = ov;
}

// ---- BMx64-tile GEMM, BK=128 ----
// BM=64: 4 waves as 2x2 (32x32 each). BM=32: 4 waves as 1x4 (32x16 each).
// AMODE 0: A = Ab; AMODE 1: A = LN(Af) via pstat_in; AMODE 2: A = merged attn
// EPI 0: QKV scatter (q pre-scaled; v [b,h,hd,t]); EPI 1: xres += v; EPI 2: GELU -> o0
// STATS 1: per-(row, colblock64) partial {sum,sumsq} of x_new -> pstat_out
template<int N, int K, int AMODE, int EPI, int STATS, int BM>
__global__ __launch_bounds__(256) void gemm_k(
    const ushort* __restrict__ Ab, const float* __restrict__ Af,
    const float* __restrict__ pstat_in, const float* __restrict__ lng, const float* __restrict__ lnb,
    const ushort* __restrict__ po, const float* __restrict__ pml,
    const ushort* __restrict__ Bt, const float* __restrict__ bias,
    float* __restrict__ xres, float* __restrict__ pstat_out,
    ushort* __restrict__ o0, ushort* __restrict__ o1, ushort* __restrict__ o2){
  constexpr int NC = (BM == 64) ? 2 : 1;      // col fragments per wave
  constexpr int NW = (BM == 64) ? 2 : 4;      // col groups (waves in col dim)
  __shared__ ushort Alds[2][BM][72];
  __shared__ ushort Blds[2][64][72];
  __shared__ float statLds[STATS ? BM : 1][NW][2];
  int tid = threadIdx.x;
  int w = tid >> 6, lane = tid & 63;
  int wr = (BM == 64) ? (w >> 1) : 0;
  int wc = (BM == 64) ? (w & 1) : w;
  int l15 = lane & 15, l4 = lane >> 4;
  int row0 = blockIdx.x * BM, col0 = blockIdx.y * 64;
  int r = tid >> 3, c8 = (tid & 7) * 8;       // r in [0,32)

  float muA = 0.f, rsA = 0.f, muB = 0.f, rsB = 0.f;
  if (AMODE == 1){
    const float4* pa = (const float4*)(pstat_in + (size_t)(row0 + r) * 8);
    float4 a0 = pa[0], a1 = pa[1];
    float s = a0.x + a0.z + a1.x + a1.z, q = a0.y + a0.w + a1.y + a1.w;
    muA = s * (1.f/256.f);
    rsA = rsqrtf(q * (1.f/256.f) - muA * muA + 1e-5f);
    if (BM == 64){
      const float4* pb = (const float4*)(pstat_in + (size_t)(row0 + r + 32) * 8);
      float4 b0 = pb[0], b1 = pb[1];
      s = b0.x + b0.z + b1.x + b1.z; q = b0.y + b0.w + b1.y + b1.w;
      muB = s * (1.f/256.f);
      rsB = rsqrtf(q * (1.f/256.f) - muB * muB + 1e-5f);
    }
  }

  f32x4 zero = {0.f, 0.f, 0.f, 0.f};
  f32x4 acc[2][NC];
  #pragma unroll
  for (int mr = 0; mr < 2; ++mr)
    #pragma unroll
    for (int nc = 0; nc < NC; ++nc) acc[mr][nc] = zero;

  for (int k0 = 0; k0 < K; k0 += 128){
    #pragma unroll
    for (int ck = 0; ck < 2; ++ck){
      int kk = k0 + ck * 64;
      // ---- stage A (BM rows) ----
      #pragma unroll
      for (int it = 0; it < BM / 32; ++it){
        int rr = r + it * 32;
        if (AMODE == 0){
          *(bf16x8*)&Alds[ck][rr][c8] = *(const bf16x8*)(Ab + (size_t)(row0 + rr) * K + kk + c8);
        } else if (AMODE == 1){
          float mu = it ? muB : muA, rs = it ? rsB : rsA;
          const float4* xp = (const float4*)(Af + (size_t)(row0 + rr) * 256 + kk + c8);
          float4 xa = xp[0], xb = xp[1];
          const float4* gp = (const float4*)(lng + kk + c8);
          const float4* bp = (const float4*)(lnb + kk + c8);
          float4 ga = gp[0], gb = gp[1], ba = bp[0], bb = bp[1];
          bf16x8 pk;
          pk[0] = (short)f2b((xa.x - mu) * rs * ga.x + ba.x);
          pk[1] = (short)f2b((xa.y - mu) * rs * ga.y + ba.y);
          pk[2] = (short)f2b((xa.z - mu) * rs * ga.z + ba.z);
          pk[3] = (short)f2b((xa.w - mu) * rs * ga.w + ba.w);
          pk[4] = (short)f2b((xb.x - mu) * rs * gb.x + bb.x);
          pk[5] = (short)f2b((xb.y - mu) * rs * gb.y + bb.y);
          pk[6] = (short)f2b((xb.z - mu) * rs * gb.z + bb.z);
          pk[7] = (short)f2b((xb.w - mu) * rs * gb.w + bb.w);
          *(bf16x8*)&Alds[ck][rr][c8] = pk;
        } else {
          int m = row0 + rr;
          int t = m & 2047, b_ = m >> 11;
          int qt = t >> 4, r16 = t & 15;
          int hh = kk >> 6;
          int u0 = (((b_ * NH + hh) << 7) + qt) << 2;
          int je = ((qt * 16 + 15) / 17) * 17 + 17; je = je < TSEQ ? je : TSEQ;
          int nch = (je + CKV - 1) >> 9;
          float mm[4]; float mg = -1e30f;
          #pragma unroll
          for (int ch = 0; ch < 4; ++ch){
            mm[ch] = (ch < nch) ? pml[(size_t)(u0 + ch) * 32 + r16 * 2] : -1e30f;
            mg = fmaxf(mg, mm[ch]);
          }
          float aw[4]; float lg = 0.f;
          #pragma unroll
          for (int ch = 0; ch < 4; ++ch){
            float ll = (ch < nch) ? pml[(size_t)(u0 + ch) * 32 + r16 * 2 + 1] : 0.f;
            aw[ch] = (ch < nch) ? __expf(mm[ch] - mg) : 0.f;
            lg += aw[ch] * ll;
          }
          float inv = 1.f / lg;
          float av[8] = {0.f,0.f,0.f,0.f,0.f,0.f,0.f,0.f};
          #pragma unroll
          for (int ch = 0; ch < 4; ++ch){
            bf16x8 pv = *(const bf16x8*)(po + (size_t)(u0 + ch) * 1024 + r16 * 64 + c8);
            #pragma unroll
            for (int j = 0; j < 8; ++j) av[j] += aw[ch] * b2f((ushort)pv[j]);
          }
          bf16x8 pk;
          #pragma unroll
          for (int j = 0; j < 8; ++j) pk[j] = (short)f2b(av[j] * inv);
          *(bf16x8*)&Alds[ck][rr][c8] = pk;
        }
      }
      // ---- stage B (64 rows) ----
      #pragma unroll
      for (int it = 0; it < 2; ++it){
        int rr = r + it * 32;
        *(bf16x8*)&Blds[ck][rr][c8] = *(const bf16x8*)(Bt + (size_t)(col0 + rr) * K + kk + c8);
      }
    }
    __syncthreads();
    #pragma unroll
    for (int ck = 0; ck < 2; ++ck){
      #pragma unroll
      for (int ks = 0; ks < 2; ++ks){
        bf16x8 af[2], bfr[NC];
        #pragma unroll
        for (int i = 0; i < 2; ++i)
          af[i] = *(const bf16x8*)&Alds[ck][wr * 32 + i * 16 + l15][ks * 32 + l4 * 8];
        #pragma unroll
        for (int i = 0; i < NC; ++i)
          bfr[i] = *(const bf16x8*)&Blds[ck][wc * (16 * NC) + i * 16 + l15][ks * 32 + l4 * 8];
        #pragma unroll
        for (int mr = 0; mr < 2; ++mr)
          #pragma unroll
          for (int nc = 0; nc < NC; ++nc)
            acc[mr][nc] = __builtin_amdgcn_mfma_f32_16x16x32_bf16(af[mr], bfr[nc], acc[mr][nc], 0, 0, 0);
      }
    }
    __syncthreads();
  }

  float sr_[2][4], q2_[2][4];
  if (STATS){
    #pragma unroll
    for (int mr = 0; mr < 2; ++mr)
      #pragma unroll
      for (int rr = 0; rr < 4; ++rr){ sr_[mr][rr] = 0.f; q2_[mr][rr] = 0.f; }
  }
  #pragma unroll
  for (int mr = 0; mr < 2; ++mr){
    #pragma unroll
    for (int nc = 0; nc < NC; ++nc){
      #pragma unroll
      for (int rr = 0; rr < 4; ++rr){
        int m = row0 + wr * 32 + mr * 16 + l4 * 4 + rr;
        int n = col0 + wc * (16 * NC) + nc * 16 + l15;
        float v = acc[mr][nc][rr] + bias[n];
        if (EPI == 0){
          int b = m >> 11, t = m & 2047;
          int which = n >> 8, hn = n & 255, hh = hn >> 6, hd = hn & 63;
          if (which == 0)      o0[(((size_t)(b * NH + hh)) * TPAD + t) * HDIM + hd] = f2b(v * 0.125f);
          else if (which == 1) o1[(((size_t)(b * NH + hh)) * TPAD + t) * HDIM + hd] = f2b(v);
          else                 o2[(((size_t)(b * NH + hh)) * HDIM + hd) * TPAD + t] = f2b(v);
        } else if (EPI == 1){
          float xn = xres[(size_t)m * 256 + n] + v;
          xres[(size_t)m * 256 + n] = xn;
          if (STATS){ sr_[mr][rr] += xn; q2_[mr][rr] += xn * xn; }
        } else {
          float uu = 0.7978845608028654f * (v + 0.044715f * v * v * v);
          float e = __expf(2.f * uu);
          float th = 1.f - 2.f / (e + 1.f);
          o0[(size_t)m * N + n] = f2b(0.5f * v * (1.f + th));
        }
      }
    }
  }
  if (STATS){
    #pragma unroll
    for (int mr = 0; mr < 2; ++mr){
      #pragma unroll
      for (int rr = 0; rr < 4; ++rr){
        float s = sr_[mr][rr], q = q2_[mr][rr];
        #pragma unroll
        for (int off = 1; off < 16; off <<= 1){ s += __shfl_xor(s, off); q += __shfl_xor(q, off); }
        if (l15 == 0){
          int rl = wr * 32 + mr * 16 + l4 * 4 + rr;
          statLds[rl][wc][0] = s;
          statLds[rl][wc][1] = q;
        }
      }
    }
    __syncthreads();
    if (tid < BM){
      float ssum = 0.f, qsum = 0.f;
      #pragma unroll
      for (int g = 0; g < NW; ++g){ ssum += statLds[tid][g][0]; qsum += statLds[tid][g][1]; }
      float2 pr; pr.x = ssum; pr.y = qsum;
      ((float2*)pstat_out)[(size_t)(row0 + tid) * 4 + blockIdx.y] = pr;
    }
  }
}

// ---- split-KV flash attention: swapped-operand QK^T, per-lane softmax,
//      defer-max rescale (T13) + setprio around MFMA clusters (T5) ----
// block = (qg 64 q-rows, ch 512-KV chunk, bh); grid (32,4,8); 4 waves x 16 q each.
__global__ __launch_bounds__(256) void attn_tile_k(const ushort* __restrict__ qq, const ushort* __restrict__ kkk,
                                                   const ushort* __restrict__ vt,
                                                   ushort* __restrict__ po, float* __restrict__ pml){
  __shared__ ushort Klds[64][72];
  __shared__ ushort Vlds[64][72];
  __shared__ ushort Plds[4][16][72];
  int tid = threadIdx.x, w = tid >> 6, lane = tid & 63;
  int l15 = lane & 15, l4 = lane >> 4;
  int qg = blockIdx.x, ch = blockIdx.y, bh = blockIdx.z;
  int r0 = qg * 64;
  int je_blk = ((r0 + 63) / 17 + 1) * 17; je_blk = je_blk < TSEQ ? je_blk : TSEQ;
  int jstart = ch * CKV;
  if (jstart >= je_blk) return;                       // idle block (uniform)
  int jend = (jstart + CKV) < je_blk ? (jstart + CKV) : je_blk;

  int i0 = r0 + w * 16;
  int je_w = ((i0 + 15) / 17 + 1) * 17; je_w = je_w < TSEQ ? je_w : TSEQ;

  const ushort* qb = qq  + (size_t)bh * TPAD * HDIM;
  const ushort* kb = kkk + (size_t)bh * TPAD * HDIM;
  const ushort* vb = vt  + (size_t)bh * HDIM * TPAD;

  int ig = i0 + l15;                                  // this lane's query row
  int ibase = (int)((unsigned)ig / 17u) * 17;         // its block start
  bf16x8 aq0 = *(const bf16x8*)(qb + (size_t)ig * HDIM + l4 * 8);
  bf16x8 aq1 = *(const bf16x8*)(qb + (size_t)ig * HDIM + 32 + l4 * 8);

  f32x4 zero = {0.f, 0.f, 0.f, 0.f};
  float m_ = -1e30f, l_ = 0.f;
  f32x4 o_[4];
  o_[0] = zero; o_[1] = zero; o_[2] = zero; o_[3] = zero;

  int sr = tid >> 2, sc = (tid & 3) * 16;             // staging: 4 threads/row, 32B each
  for (int j0 = jstart; j0 < jend; j0 += 64){
    __syncthreads();
    *(bf16x8*)&Klds[sr][sc]     = *(const bf16x8*)(kb + (size_t)(j0 + sr) * HDIM + sc);
    *(bf16x8*)&Klds[sr][sc + 8] = *(const bf16x8*)(kb + (size_t)(j0 + sr) * HDIM + sc + 8);
    *(bf16x8*)&Vlds[sr][sc]     = *(const bf16x8*)(vb + (size_t)sr * TPAD + j0 + sc);
    *(bf16x8*)&Vlds[sr][sc + 8] = *(const bf16x8*)(vb + (size_t)sr * TPAD + j0 + sc + 8);
    __syncthreads();
    if (j0 >= je_w) continue;
    f32x4 s[4];
    __builtin_amdgcn_s_setprio(1);
    #pragma unroll
    for (int f = 0; f < 4; ++f){
      bf16x8 kf = *(const bf16x8*)&Klds[f * 16 + l15][l4 * 8];
      s[f] = __builtin_amdgcn_mfma_f32_16x16x32_bf16(kf, aq0, zero, 0, 0, 0);
    }
    #pragma unroll
    for (int f = 0; f < 4; ++f){
      bf16x8 kf = *(const bf16x8*)&Klds[f * 16 + l15][32 + l4 * 8];
      s[f] = __builtin_amdgcn_mfma_f32_16x16x32_bf16(kf, aq1, s[f], 0, 0, 0);
    }
    __builtin_amdgcn_s_setprio(0);
    if (j0 + 63 > i0){
      #pragma unroll
      for (int f = 0; f < 4; ++f){
        #pragma unroll
        for (int rr = 0; rr < 4; ++rr){
          int jg = j0 + f * 16 + l4 * 4 + rr;
          bool ok = (jg <= ig) || ((unsigned)(jg - ibase) < 17u);
          s[f][rr] = ok ? s[f][rr] : -1e30f;
        }
      }
    }
    float mf0 = fmaxf(fmaxf(s[0][0], s[0][1]), fmaxf(s[0][2], s[0][3]));
    float mf1 = fmaxf(fmaxf(s[1][0], s[1][1]), fmaxf(s[1][2], s[1][3]));
    float mf2 = fmaxf(fmaxf(s[2][0], s[2][1]), fmaxf(s[2][2], s[2][3]));
    float mf3 = fmaxf(fmaxf(s[3][0], s[3][1]), fmaxf(s[3][2], s[3][3]));
    float mx = fmaxf(fmaxf(mf0, mf1), fmaxf(mf2, mf3));
    mx = fmaxf(mx, __shfl_xor(mx, 16));
    mx = fmaxf(mx, __shfl_xor(mx, 32));
    // defer-max: skip O/l rescale when max growth is bounded (P <= e^8, bf16-safe)
    float mn = m_;
    if (!__all(mx - m_ <= 8.f)){
      mn = fmaxf(m_, mx);
      float alpha = __expf(m_ - mn);
      l_ *= alpha;
      #pragma unroll
      for (int f = 0; f < 4; ++f) o_[f] *= alpha;
      m_ = mn;
    }
    float ps = 0.f;
    #pragma unroll
    for (int f = 0; f < 4; ++f){
      bf16x4 pk;
      #pragma unroll
      for (int rr = 0; rr < 4; ++rr){
        float p = __expf(s[f][rr] - mn);
        ps += p;
        pk[rr] = (short)f2b(p);
      }
      *(bf16x4*)&Plds[w][l15][f * 16 + l4 * 4] = pk;
    }
    ps += __shfl_xor(ps, 16);
    ps += __shfl_xor(ps, 32);
    l_ += ps;
    __builtin_amdgcn_s_setprio(1);
    #pragma unroll
    for (int ks = 0; ks < 2; ++ks){
      bf16x8 pf = *(const bf16x8*)&Plds[w][l15][ks * 32 + l4 * 8];
      #pragma unroll
      for (int f = 0; f < 4; ++f){
        bf16x8 vf = *(const bf16x8*)&Vlds[f * 16 + l15][ks * 32 + l4 * 8];
        o_[f] = __builtin_amdgcn_mfma_f32_16x16x32_bf16(vf, pf, o_[f], 0, 0, 0);
      }
    }
    __builtin_amdgcn_s_setprio(0);
  }
  int qt = qg * 4 + w;
  int u = ((bh << 7) + qt) * 4 + ch;
  size_t ob = (size_t)u * 1024;
  #pragma unroll
  for (int f = 0; f < 4; ++f){
    bf16x4 pk;
    #pragma unroll
    for (int rr = 0; rr < 4; ++rr) pk[rr] = (short)f2b(o_[f][rr]);
    *(bf16x4*)&po[ob + (size_t)l15 * 64 + f * 16 + l4 * 4] = pk;
  }
  if (l4 == 0){
    pml[(size_t)u * 32 + l15 * 2 + 0] = m_;
    pml[(size_t)u * 32 + l15 * 2 + 1] = l_;
  }
}

extern "C" void kernel_launch(void* const* d_in, const int* in_sizes, int n_in,
                              void* d_out, int out_size, void* d_ws, size_t ws_size,
                              hipStream_t stream){
  const float* seq    = (const float*)d_in[0];
  const float* ln1_g  = (const float*)d_in[1];
  const float* ln1_b  = (const float*)d_in[2];
  const float* wq     = (const float*)d_in[3];
  const float* bq     = (const float*)d_in[4];
  const float* wk     = (const float*)d_in[5];
  const float* bk     = (const float*)d_in[6];
  const float* wv     = (const float*)d_in[7];
  const float* bv     = (const float*)d_in[8];
  const float* wproj  = (const float*)d_in[9];
  const float* bproj  = (const float*)d_in[10];
  const float* ln2_g  = (const float*)d_in[11];
  const float* ln2_b  = (const float*)d_in[12];
  const float* w1     = (const float*)d_in[13];
  const float* b1     = (const float*)d_in[14];
  const float* w2     = (const float*)d_in[15];
  const float* b2     = (const float*)d_in[16];
  const float* lnf_g  = (const float*)d_in[17];
  const float* lnf_b  = (const float*)d_in[18];

  size_t off = 0;
  char* base = (char*)d_ws;
  auto carve = [&](size_t bytes) -> void* {
    void* p = base + off;
    off += (bytes + 255) & ~(size_t)255;
    return p;
  };
  float*  x      = (float*) carve((size_t)MPAD * DMOD * 4);
  ushort* qbuf   = (ushort*)carve((size_t)BSZ * NH * TPAD * HDIM * 2);
  ushort* kbuf   = (ushort*)carve((size_t)BSZ * NH * TPAD * HDIM * 2);
  ushort* vtbuf  = (ushort*)carve((size_t)BSZ * NH * TPAD * HDIM * 2);
  ushort* mid    = (ushort*)carve((size_t)MPAD * DFF * 2);
  ushort* wqkvT  = (ushort*)carve((size_t)NL * 768 * 256 * 2);
  ushort* wprojT = (ushort*)carve((size_t)NL * 256 * 256 * 2);
  ushort* w1T    = (ushort*)carve((size_t)NL * 1024 * 256 * 2);
  ushort* w2T    = (ushort*)carve((size_t)NL * 256 * 1024 * 2);
  float*  bqkv   = (float*) carve((size_t)NL * 768 * 4);
  ushort* po     = (ushort*)carve((size_t)4096 * 1024 * 2);
  float*  pml    = (float*) carve((size_t)4096 * 32 * 4);
  float*  pstatA = (float*) carve((size_t)MPAD * 8 * 4);
  float*  pstatB = (float*) carve((size_t)MPAD * 8 * 4);
  if (off > ws_size) return;

  // fused prep: all transposes + bias concat + input copy/stats in ONE dispatch
  prep_k<<<dim3(2974), dim3(256), 0, stream>>>(
      seq, x, pstatA, wq, wk, wv, wproj, w1, w2,
      wqkvT, wprojT, w1T, w2T, bq, bk, bv, bqkv);

  for (int l = 0; l < NL; ++l){
    gemm_k<768,256,1,0,0,64><<<dim3(64,12), dim3(256), 0, stream>>>(
        nullptr, x, pstatA, ln1_g + l*256, ln1_b + l*256, nullptr, nullptr,
        wqkvT + (size_t)l*768*256, bqkv + l*768, nullptr, nullptr, qbuf, kbuf, vtbuf);
    attn_tile_k<<<dim3(32,4,8), dim3(256), 0, stream>>>(qbuf, kbuf, vtbuf, po, pml);
    gemm_k<256,256,2,1,1,32><<<dim3(128,4), dim3(256), 0, stream>>>(
        nullptr, nullptr, nullptr, nullptr, nullptr, po, pml,
        wprojT + (size_t)l*256*256, bproj + l*256, x, pstatB, nullptr, nullptr, nullptr);
    gemm_k<1024,256,1,2,0,64><<<dim3(64,16), dim3(256), 0, stream>>>(
        nullptr, x, pstatB, ln2_g + l*256, ln2_b + l*256, nullptr, nullptr,
        w1T + (size_t)l*1024*256, b1 + l*1024, nullptr, nullptr, mid, nullptr, nullptr);
    gemm_k<256,1024,0,1,1,32><<<dim3(128,4), dim3(256), 0, stream>>>(
        mid, nullptr, nullptr, nullptr, nullptr, nullptr, nullptr,
        w2T + (size_t)l*256*1024, b2 + l*256, x, pstatA, nullptr, nullptr, nullptr);
  }
  lnf_k<<<dim3(BSZ*TSEQ/4), dim3(256), 0, stream>>>(x, pstatA, lnf_g, lnf_b, (float*)d_out);
}